// Round 2
// baseline (40166.254 us; speedup 1.0000x reference)
//
#include <hip/hip_runtime.h>
#include <math.h>

#define BB 32
#define SS 48
#define HH 1024
#define EE 256
#define VOC 32000
#define GEN 32
#define G3 3072
#define CH 256   // k-chunk for persistent encoder

__device__ __forceinline__ float sigf(float x) { return 1.f / (1.f + expf(-x)); }

// ---------------- embedding for encoder input ----------------
__global__ __launch_bounds__(256) void embed_en_k(const int* __restrict__ inputs,
                                                  const float* __restrict__ emb,
                                                  float* __restrict__ x) {
    int i = blockIdx.x * 256 + threadIdx.x;   // < BB*SS*EE
    int row = i >> 8;
    int e = i & 255;
    x[i] = emb[(size_t)inputs[row] * EE + e];
}

// ---------------- fp32 GEMM 128x128 tile, 8x8 micro ----------------
__global__ __launch_bounds__(256) void gemm128(const float* __restrict__ A,
                                               const float* __restrict__ Bm,
                                               const float* __restrict__ bias,
                                               float* __restrict__ C,
                                               int N, int K) {
    __shared__ float As[16][132];
    __shared__ float Bs[16][132];
    int tid = threadIdx.x;
    int tx = tid & 15, ty = tid >> 4;
    int arow = blockIdx.y * 128, bcol = blockIdx.x * 128;
    int am = tid >> 1;            // 0..127
    int ak = (tid & 1) * 8;       // 0 or 8
    int bk = tid >> 4;            // 0..15
    int bn = (tid & 15) * 8;      // 0..120
    float acc[8][8] = {};
    for (int k0 = 0; k0 < K; k0 += 16) {
        float4 a0 = *(const float4*)(A + (size_t)(arow + am) * K + k0 + ak);
        float4 a1 = *(const float4*)(A + (size_t)(arow + am) * K + k0 + ak + 4);
        float4 b0 = *(const float4*)(Bm + (size_t)(k0 + bk) * N + bcol + bn);
        float4 b1 = *(const float4*)(Bm + (size_t)(k0 + bk) * N + bcol + bn + 4);
        As[ak + 0][am] = a0.x; As[ak + 1][am] = a0.y;
        As[ak + 2][am] = a0.z; As[ak + 3][am] = a0.w;
        As[ak + 4][am] = a1.x; As[ak + 5][am] = a1.y;
        As[ak + 6][am] = a1.z; As[ak + 7][am] = a1.w;
        *(float4*)&Bs[bk][bn] = b0;
        *(float4*)&Bs[bk][bn + 4] = b1;
        __syncthreads();
#pragma unroll
        for (int kk = 0; kk < 16; ++kk) {
            float a[8], b[8];
            *(float4*)&a[0] = *(const float4*)&As[kk][ty * 8];
            *(float4*)&a[4] = *(const float4*)&As[kk][ty * 8 + 4];
            *(float4*)&b[0] = *(const float4*)&Bs[kk][tx * 8];
            *(float4*)&b[4] = *(const float4*)&Bs[kk][tx * 8 + 4];
#pragma unroll
            for (int i = 0; i < 8; ++i)
#pragma unroll
                for (int j = 0; j < 8; ++j) acc[i][j] += a[i] * b[j];
        }
        __syncthreads();
    }
    float bb[8];
    *(float4*)&bb[0] = *(const float4*)&bias[bcol + tx * 8];
    *(float4*)&bb[4] = *(const float4*)&bias[bcol + tx * 8 + 4];
#pragma unroll
    for (int i = 0; i < 8; ++i) {
        size_t row = arow + ty * 8 + i;
        float4 o0 = make_float4(acc[i][0] + bb[0], acc[i][1] + bb[1],
                                acc[i][2] + bb[2], acc[i][3] + bb[3]);
        float4 o1 = make_float4(acc[i][4] + bb[4], acc[i][5] + bb[5],
                                acc[i][6] + bb[6], acc[i][7] + bb[7]);
        *(float4*)(C + row * N + bcol + tx * 8) = o0;
        *(float4*)(C + row * N + bcol + tx * 8 + 4) = o1;
    }
}

// ---------------- persistent encoder GRU layer ----------------
// grid 256 blocks x 384 threads, 1 block/CU (84KB LDS). Each block owns 4
// h-columns (12 gate-cols), keeps U-slice in LDS for all 48 steps.
// Software grid barrier between steps (device-scope atomics).
__global__ __launch_bounds__(384, 1) void enc_layer_persist(
    const float* __restrict__ gi,   // [B*S][3072] = x@W + b0
    const float* __restrict__ U,    // [1024][3072]
    const float* __restrict__ b1,
    float* __restrict__ buf0,       // ping (zeroed), final state here
    float* __restrict__ buf1,       // pong (zeroed)
    float* __restrict__ seqout,     // [B*S][1024]
    int* __restrict__ barcnt) {
    __shared__ float Us[12][1024];      // 48 KB  (colg = gate*4 + c)
    __shared__ float hs[32][260];       // 33.3 KB (one CH-chunk of h)
    __shared__ float ghs[12][33];       // reduced gh
    const int tid = threadIdx.x;
    const int c0 = blockIdx.x * 4;
    // one-time: load U slice (colg = g*4+c -> global col g*1024 + c0 + c)
    for (int i = tid; i < 12 * 1024; i += 384) {
        int colg = i % 12;
        int k = i / 12;
        Us[colg][k] = U[(size_t)k * G3 + (colg >> 2) * HH + c0 + (colg & 3)];
    }
    const int ks = tid & 31;        // k-slice 0..31
    const int outIdx = tid >> 5;    // 0..11
    const int cq = outIdx >> 2;     // gate-quad 0..2 (== gate)
    const int mo = outIdx & 3;      // m-oct 0..3
    int barcount = 0;
    __syncthreads();
    for (int t = 0; t < SS; ++t) {
        const float* hin = (t & 1) ? buf1 : buf0;
        float* hout = (t & 1) ? buf0 : buf1;
        float acc[4][8];
#pragma unroll
        for (int a = 0; a < 4; ++a)
#pragma unroll
            for (int b = 0; b < 8; ++b) acc[a][b] = 0.f;
        for (int ch = 0; ch < HH / CH; ++ch) {
            for (int i = tid; i < 32 * (CH / 4); i += 384) {
                int m = i >> 6, q = i & 63;
                *(float4*)&hs[m][q * 4] =
                    *(const float4*)&hin[m * HH + ch * CH + q * 4];
            }
            __syncthreads();
#pragma unroll
            for (int j = 0; j < 2; ++j) {
                int kb = (j * 32 + ks) * 4;
                float4 uv[4];
#pragma unroll
                for (int ci = 0; ci < 4; ++ci)
                    uv[ci] = *(const float4*)&Us[cq * 4 + ci][ch * CH + kb];
#pragma unroll
                for (int mi = 0; mi < 8; ++mi) {
                    float4 hv = *(const float4*)&hs[mo * 8 + mi][kb];
#pragma unroll
                    for (int ci = 0; ci < 4; ++ci)
                        acc[ci][mi] += hv.x * uv[ci].x + hv.y * uv[ci].y +
                                       hv.z * uv[ci].z + hv.w * uv[ci].w;
                }
            }
            __syncthreads();
        }
        // reduce over 32 ks lanes (contiguous within wave-half)
#pragma unroll
        for (int ci = 0; ci < 4; ++ci)
#pragma unroll
            for (int mi = 0; mi < 8; ++mi) {
                float v = acc[ci][mi];
                v += __shfl_xor(v, 1, 64);
                v += __shfl_xor(v, 2, 64);
                v += __shfl_xor(v, 4, 64);
                v += __shfl_xor(v, 8, 64);
                v += __shfl_xor(v, 16, 64);
                if (ks == 0) ghs[cq * 4 + ci][mo * 8 + mi] = v;
            }
        __syncthreads();
        if (tid < 128) {
            int m = tid & 31, c = tid >> 5;      // c 0..3
            int col = c0 + c;
            float ghz = ghs[c][m] + b1[col];
            float ghr = ghs[4 + c][m] + b1[HH + col];
            float ghh = ghs[8 + c][m] + b1[2 * HH + col];
            const float* gir = gi + ((size_t)m * SS + t) * G3;
            float z = sigf(gir[col] + ghz);
            float r = sigf(gir[HH + col] + ghr);
            float nn = tanhf(gir[2 * HH + col] + r * ghh);
            float h = z * hin[m * HH + col] + (1.f - z) * nn;
            hout[m * HH + col] = h;
            seqout[((size_t)m * SS + t) * HH + col] = h;
        }
        // ---- grid barrier ----
        __threadfence();
        __syncthreads();
        if (tid == 0) {
            __hip_atomic_fetch_add(barcnt, 1, __ATOMIC_ACQ_REL,
                                   __HIP_MEMORY_SCOPE_AGENT);
            ++barcount;
            int target = barcount * (int)gridDim.x;
            while (__hip_atomic_load(barcnt, __ATOMIC_ACQUIRE,
                                     __HIP_MEMORY_SCOPE_AGENT) < target) {}
        }
        __syncthreads();
    }
}

// ---------------- M=32 GEMM (q / logits) + optional fused row-max ----------------
// grid N/128, 256 thr: nq = tid&31 (4 cols), mg = tid>>5 (4 m's). K%128==0.
__global__ __launch_bounds__(256) void mgemm(const float* __restrict__ A,
                                             const float* __restrict__ Bm,
                                             const float* __restrict__ bias,
                                             float* __restrict__ C,
                                             int K, int N, int ldc,
                                             float* __restrict__ pmv,
                                             int* __restrict__ pmi) {
    __shared__ float As_[128][36];   // transposed chunk [k][m]
    int tid = threadIdx.x;
    int nq = tid & 31, mg = tid >> 5;
    int ncol = blockIdx.x * 128 + nq * 4;
    const float* Bp = Bm + ncol;
    float acc[4][4] = {};
    for (int ch = 0; ch < K / 128; ++ch) {
#pragma unroll
        for (int it = 0; it < 4; ++it) {
            int idx = it * 256 + tid;      // 0..1023
            int m = idx >> 5, q = idx & 31;
            float4 v = *(const float4*)(A + (size_t)m * K + ch * 128 + q * 4);
            As_[q * 4 + 0][m] = v.x; As_[q * 4 + 1][m] = v.y;
            As_[q * 4 + 2][m] = v.z; As_[q * 4 + 3][m] = v.w;
        }
        __syncthreads();
#pragma unroll 4
        for (int k = 0; k < 128; ++k) {
            float4 av = *(const float4*)&As_[k][mg * 4];
            float4 bv = *(const float4*)(Bp + (size_t)(ch * 128 + k) * N);
            acc[0][0] += av.x * bv.x; acc[0][1] += av.x * bv.y;
            acc[0][2] += av.x * bv.z; acc[0][3] += av.x * bv.w;
            acc[1][0] += av.y * bv.x; acc[1][1] += av.y * bv.y;
            acc[1][2] += av.y * bv.z; acc[1][3] += av.y * bv.w;
            acc[2][0] += av.z * bv.x; acc[2][1] += av.z * bv.y;
            acc[2][2] += av.z * bv.z; acc[2][3] += av.z * bv.w;
            acc[3][0] += av.w * bv.x; acc[3][1] += av.w * bv.y;
            acc[3][2] += av.w * bv.z; acc[3][3] += av.w * bv.w;
        }
        __syncthreads();
    }
    float4 cv = *(const float4*)&bias[ncol];
#pragma unroll
    for (int mi = 0; mi < 4; ++mi) {
        acc[mi][0] += cv.x; acc[mi][1] += cv.y;
        acc[mi][2] += cv.z; acc[mi][3] += cv.w;
        int row = mg * 4 + mi;
        *(float4*)(C + (size_t)row * ldc + ncol) =
            make_float4(acc[mi][0], acc[mi][1], acc[mi][2], acc[mi][3]);
    }
    if (pmv) {
        int nbk = gridDim.x;
#pragma unroll
        for (int mi = 0; mi < 4; ++mi) {
            float best = acc[mi][0]; int bidx = ncol;
#pragma unroll
            for (int nj = 1; nj < 4; ++nj)
                if (acc[mi][nj] > best) { best = acc[mi][nj]; bidx = ncol + nj; }
#pragma unroll
            for (int o = 1; o < 32; o <<= 1) {
                float pv = __shfl_xor(best, o, 64);
                int pi = __shfl_xor(bidx, o, 64);
                if (pv > best || (pv == best && pi < bidx)) { best = pv; bidx = pi; }
            }
            if (nq == 0) {
                int row = mg * 4 + mi;
                pmv[row * nbk + blockIdx.x] = best;
                pmi[row * nbk + blockIdx.x] = bidx;
            }
        }
    }
}

// ---------------- final argmax over per-block partials ----------------
__global__ __launch_bounds__(256) void argmax_final(const float* __restrict__ pmv,
                                                    const int* __restrict__ pmi,
                                                    int nb, int* __restrict__ dec_in) {
    int b = blockIdx.x;
    int tid = threadIdx.x;
    __shared__ float sv[256];
    __shared__ int si[256];
    float best = -3.4e38f; int bi = 0x7fffffff;
    for (int i = tid; i < nb; i += 256) {
        float v = pmv[(size_t)b * nb + i];
        int ix = pmi[(size_t)b * nb + i];
        if (v > best || (v == best && ix < bi)) { best = v; bi = ix; }
    }
    sv[tid] = best; si[tid] = bi;
    __syncthreads();
    for (int s = 128; s; s >>= 1) {
        if (tid < s) {
            if (sv[tid + s] > sv[tid] ||
                (sv[tid + s] == sv[tid] && si[tid + s] < si[tid])) {
                sv[tid] = sv[tid + s]; si[tid] = si[tid + s];
            }
        }
        __syncthreads();
    }
    if (tid == 0) dec_in[b] = si[0];
}

// ---------------- fused decoder GRU (zero initial state), k-split x4 ----------------
// grid 128 blocks (8 h-cols each), 256 thr = 2 nq x 32 m x 4 kh.
__global__ __launch_bounds__(256) void dec_gru2(const float* __restrict__ A, int K,
                                                const float* __restrict__ W,
                                                const float* __restrict__ b0,
                                                const float* __restrict__ b1,
                                                float* __restrict__ hout) {
    __shared__ float part[3][64][13];
    int tid = threadIdx.x;
    int nq = tid & 1, m = (tid >> 1) & 31, kh = tid >> 6;
    int cb = blockIdx.x * 8 + nq * 4;
    float acc[3][4] = {};
    int kslice = K >> 2;
    const float* Ap = A + (size_t)m * K;
    int k0 = kh * kslice;
#pragma unroll 4
    for (int k = k0; k < k0 + kslice; ++k) {
        float av = Ap[k];
        const float* Wr = W + (size_t)k * G3 + cb;
#pragma unroll
        for (int g = 0; g < 3; ++g) {
            float4 wv = *(const float4*)(Wr + g * HH);
            acc[g][0] += av * wv.x; acc[g][1] += av * wv.y;
            acc[g][2] += av * wv.z; acc[g][3] += av * wv.w;
        }
    }
    int idx = m * 2 + nq;
    if (kh) {
#pragma unroll
        for (int g = 0; g < 3; ++g)
#pragma unroll
            for (int j = 0; j < 4; ++j)
                part[kh - 1][idx][g * 4 + j] = acc[g][j];
    }
    __syncthreads();
    if (kh == 0) {
        float vals[3][4];
#pragma unroll
        for (int g = 0; g < 3; ++g)
#pragma unroll
            for (int j = 0; j < 4; ++j)
                vals[g][j] = acc[g][j] + part[0][idx][g * 4 + j] +
                             part[1][idx][g * 4 + j] + part[2][idx][g * 4 + j];
        float4 hv;
        float* hvp = (float*)&hv;
#pragma unroll
        for (int j = 0; j < 4; ++j) {
            int c = cb + j;
            float z = sigf(vals[0][j] + b0[c] + b1[c]);
            float r = sigf(vals[1][j] + b0[HH + c] + b1[HH + c]);
            float nn = tanhf(vals[2][j] + b0[2 * HH + c] + r * b1[2 * HH + c]);
            hvp[j] = (1.f - z) * nn;
        }
        *(float4*)(hout + (size_t)m * HH + cb) = hv;
    }
}

// ---------------- Bahdanau attention + context + decoder input build ----------------
__global__ __launch_bounds__(256) void attn_ctx(const float* __restrict__ qb,
                                                const float* __restrict__ enc_proj,
                                                const float* __restrict__ enc_out,
                                                const float* __restrict__ vvec,
                                                const float* __restrict__ vb,
                                                const float* __restrict__ emb_fr,
                                                const int* __restrict__ dec_in,
                                                float* __restrict__ xt) {
    int b = blockIdx.x;
    int tid = threadIdx.x;
    int wave = tid >> 6, lane = tid & 63;
    __shared__ float sc[SS];
    __shared__ float wsm[SS];
    const float* q = qb + (size_t)b * HH;
    for (int s = wave; s < SS; s += 4) {
        const float* ep = enc_proj + (size_t)(b * SS + s) * HH;
        float sum = 0.f;
        for (int h = lane; h < HH; h += 64)
            sum += tanhf(q[h] + ep[h]) * vvec[h];
#pragma unroll
        for (int o = 32; o; o >>= 1) sum += __shfl_xor(sum, o, 64);
        if (lane == 0) sc[s] = sum + vb[0];
    }
    __syncthreads();
    if (tid < 64) {
        float v = (lane < SS) ? sc[lane] : -3.4e38f;
        float m = v;
#pragma unroll
        for (int o = 32; o; o >>= 1) m = fmaxf(m, __shfl_xor(m, o, 64));
        float e = (lane < SS) ? expf(v - m) : 0.f;
        float ssum = e;
#pragma unroll
        for (int o = 32; o; o >>= 1) ssum += __shfl_xor(ssum, o, 64);
        if (lane < SS) wsm[lane] = e / ssum;
    }
    __syncthreads();
    {
        float4 cx = make_float4(0.f, 0.f, 0.f, 0.f);
#pragma unroll 4
        for (int s = 0; s < SS; ++s) {
            float w = wsm[s];
            float4 e = *(const float4*)&enc_out[(size_t)(b * SS + s) * HH + tid * 4];
            cx.x += w * e.x; cx.y += w * e.y; cx.z += w * e.z; cx.w += w * e.w;
        }
        *(float4*)&xt[(size_t)b * (HH + EE) + tid * 4] = cx;
    }
    {
        int tok = dec_in[b];
        xt[(size_t)b * (HH + EE) + HH + tid] = emb_fr[(size_t)tok * EE + tid];
    }
}

// ---------------- decoder init ----------------
__global__ __launch_bounds__(256) void init_dec(float* __restrict__ out,
                                                int* __restrict__ dec_in,
                                                const int* __restrict__ start_id) {
    int idx = blockIdx.x * 256 + threadIdx.x;
    int sid = start_id[0];
    int b = idx / VOC, v = idx % VOC;
    out[(size_t)b * (GEN * VOC) + v] = (v == sid) ? 1.f : 0.f;
    if (blockIdx.x == 0 && threadIdx.x < BB) dec_in[threadIdx.x] = sid;
}

extern "C" void kernel_launch(void* const* d_in, const int* in_sizes, int n_in,
                              void* d_out, int out_size, void* d_ws, size_t ws_size,
                              hipStream_t stream) {
    const int*   inputs   = (const int*)d_in[0];
    const int*   start_id = (const int*)d_in[2];
    const float* emb_en   = (const float*)d_in[3];
    const float* emb_fr   = (const float*)d_in[4];
    const float* enc_W0   = (const float*)d_in[5];
    const float* enc_U0   = (const float*)d_in[6];
    const float* enc_b0   = (const float*)d_in[7];
    const float* enc_W1   = (const float*)d_in[8];
    const float* enc_U1   = (const float*)d_in[9];
    const float* enc_b1   = (const float*)d_in[10];
    const float* dec_W0   = (const float*)d_in[11];
    const float* dec_b0   = (const float*)d_in[13];
    const float* dec_W1   = (const float*)d_in[14];
    const float* dec_b1   = (const float*)d_in[16];
    const float* attn_W1  = (const float*)d_in[17];
    const float* attn_b1  = (const float*)d_in[18];
    const float* attn_W2  = (const float*)d_in[19];
    const float* attn_b2  = (const float*)d_in[20];
    const float* attn_V   = (const float*)d_in[21];
    const float* attn_Vb  = (const float*)d_in[22];
    const float* fc_W     = (const float*)d_in[23];
    const float* fc_b     = (const float*)d_in[24];
    float* out = (float*)d_out;
    float* ws  = (float*)d_ws;

    // workspace carve (floats)
    float* giA   = ws;                                // 4,718,592
    float* x_emb = giA + (size_t)BB * SS * G3;        // 393,216
    float* seq0  = x_emb + (size_t)BB * SS * EE;      // 1,572,864
    float* encO  = seq0 + (size_t)BB * SS * HH;       // 1,572,864
    float* encP  = encO + (size_t)BB * SS * HH;       // 1,572,864
    float* hA    = encP + (size_t)BB * SS * HH;       // 32,768
    float* hB    = hA + BB * HH;                      // 32,768
    float* qbuf  = hB + BB * HH;                      // 32,768
    float* xt    = qbuf + BB * HH;                    // 40,960
    float* h1    = xt + BB * (HH + EE);               // 32,768
    int*   dec_in = (int*)(h1 + BB * HH);             // 32 ints
    float* pmv   = (float*)(dec_in + 32);             // 32*250
    int*   pmi   = (int*)(pmv + 32 * 250);            // 32*250
    int*   barcnt = pmi + 32 * 250;                   // 2 ints

    hipMemsetAsync(barcnt, 0, 2 * sizeof(int), stream);

    // ---- encoder ----
    embed_en_k<<<(BB * SS * EE) / 256, 256, 0, stream>>>(inputs, emb_en, x_emb);
    gemm128<<<dim3(G3 / 128, (BB * SS) / 128), 256, 0, stream>>>(
        x_emb, enc_W0, enc_b0, giA, G3, EE);
    hipMemsetAsync(hA, 0, 2 * BB * HH * sizeof(float), stream);
    enc_layer_persist<<<256, 384, 0, stream>>>(giA, enc_U0, enc_b0 + G3,
                                               hA, hB, seq0, barcnt);
    gemm128<<<dim3(G3 / 128, (BB * SS) / 128), 256, 0, stream>>>(
        seq0, enc_W1, enc_b1, giA, G3, HH);
    hipMemsetAsync(hA, 0, 2 * BB * HH * sizeof(float), stream);
    enc_layer_persist<<<256, 384, 0, stream>>>(giA, enc_U1, enc_b1 + G3,
                                               hA, hB, encO, barcnt + 1);
    // final hidden now in hA
    gemm128<<<dim3(HH / 128, (BB * SS) / 128), 256, 0, stream>>>(
        encO, attn_W2, attn_b2, encP, HH, HH);

    // ---- decoder ----
    init_dec<<<(BB * VOC) / 256, 256, 0, stream>>>(out, dec_in, start_id);
    for (int step = 1; step < GEN; ++step) {
        mgemm<<<HH / 128, 256, 0, stream>>>(hA, attn_W1, attn_b1, qbuf,
                                            HH, HH, HH, nullptr, nullptr);
        attn_ctx<<<BB, 256, 0, stream>>>(qbuf, encP, encO, attn_V, attn_Vb,
                                         emb_fr, dec_in, xt);
        dec_gru2<<<HH / 8, 256, 0, stream>>>(xt, HH + EE, dec_W0, dec_b0,
                                             dec_b0 + G3, h1);
        dec_gru2<<<HH / 8, 256, 0, stream>>>(h1, HH, dec_W1, dec_b1,
                                             dec_b1 + G3, hA);
        mgemm<<<VOC / 128, 256, 0, stream>>>(hA, fc_W, fc_b,
                                             out + (size_t)step * VOC,
                                             HH, VOC, GEN * VOC, pmv, pmi);
        if (step < GEN - 1)
            argmax_final<<<BB, 256, 0, stream>>>(pmv, pmi, VOC / 128, dec_in);
    }
}

// Round 3
// 25748.938 us; speedup vs baseline: 1.5599x; 1.5599x over previous
//
#include <hip/hip_runtime.h>
#include <math.h>

#define BB 32
#define SS 48
#define HH 1024
#define EE 256
#define VOC 32000
#define GEN 32
#define G3 3072
#define CH 256   // k-chunk for persistent encoder

__device__ __forceinline__ float sigf(float x) { return 1.f / (1.f + expf(-x)); }

// ---------------- embedding for encoder input ----------------
__global__ __launch_bounds__(256) void embed_en_k(const int* __restrict__ inputs,
                                                  const float* __restrict__ emb,
                                                  float* __restrict__ x) {
    int i = blockIdx.x * 256 + threadIdx.x;   // < BB*SS*EE
    int row = i >> 8;
    int e = i & 255;
    x[i] = emb[(size_t)inputs[row] * EE + e];
}

// ---------------- fp32 GEMM 128x128 tile, 8x8 micro ----------------
__global__ __launch_bounds__(256) void gemm128(const float* __restrict__ A,
                                               const float* __restrict__ Bm,
                                               const float* __restrict__ bias,
                                               float* __restrict__ C,
                                               int N, int K) {
    __shared__ float As[16][132];
    __shared__ float Bs[16][132];
    int tid = threadIdx.x;
    int tx = tid & 15, ty = tid >> 4;
    int arow = blockIdx.y * 128, bcol = blockIdx.x * 128;
    int am = tid >> 1;            // 0..127
    int ak = (tid & 1) * 8;       // 0 or 8
    int bk = tid >> 4;            // 0..15
    int bn = (tid & 15) * 8;      // 0..120
    float acc[8][8] = {};
    for (int k0 = 0; k0 < K; k0 += 16) {
        float4 a0 = *(const float4*)(A + (size_t)(arow + am) * K + k0 + ak);
        float4 a1 = *(const float4*)(A + (size_t)(arow + am) * K + k0 + ak + 4);
        float4 b0 = *(const float4*)(Bm + (size_t)(k0 + bk) * N + bcol + bn);
        float4 b1 = *(const float4*)(Bm + (size_t)(k0 + bk) * N + bcol + bn + 4);
        As[ak + 0][am] = a0.x; As[ak + 1][am] = a0.y;
        As[ak + 2][am] = a0.z; As[ak + 3][am] = a0.w;
        As[ak + 4][am] = a1.x; As[ak + 5][am] = a1.y;
        As[ak + 6][am] = a1.z; As[ak + 7][am] = a1.w;
        *(float4*)&Bs[bk][bn] = b0;
        *(float4*)&Bs[bk][bn + 4] = b1;
        __syncthreads();
#pragma unroll
        for (int kk = 0; kk < 16; ++kk) {
            float a[8], b[8];
            *(float4*)&a[0] = *(const float4*)&As[kk][ty * 8];
            *(float4*)&a[4] = *(const float4*)&As[kk][ty * 8 + 4];
            *(float4*)&b[0] = *(const float4*)&Bs[kk][tx * 8];
            *(float4*)&b[4] = *(const float4*)&Bs[kk][tx * 8 + 4];
#pragma unroll
            for (int i = 0; i < 8; ++i)
#pragma unroll
                for (int j = 0; j < 8; ++j) acc[i][j] += a[i] * b[j];
        }
        __syncthreads();
    }
    float bb[8];
    *(float4*)&bb[0] = *(const float4*)&bias[bcol + tx * 8];
    *(float4*)&bb[4] = *(const float4*)&bias[bcol + tx * 8 + 4];
#pragma unroll
    for (int i = 0; i < 8; ++i) {
        size_t row = arow + ty * 8 + i;
        float4 o0 = make_float4(acc[i][0] + bb[0], acc[i][1] + bb[1],
                                acc[i][2] + bb[2], acc[i][3] + bb[3]);
        float4 o1 = make_float4(acc[i][4] + bb[4], acc[i][5] + bb[5],
                                acc[i][6] + bb[6], acc[i][7] + bb[7]);
        *(float4*)(C + row * N + bcol + tx * 8) = o0;
        *(float4*)(C + row * N + bcol + tx * 8 + 4) = o1;
    }
}

// ---------------- persistent encoder GRU layer ----------------
// grid 256 blocks x 384 threads, 1 block/CU (84KB LDS). Flag-array grid
// barrier: each block release-stores its own padded flag; 256 threads each
// acquire-poll one flag. No same-line RMW (previous version: 256 serialized
// agent-scope RMWs = 162us/step).
__global__ __launch_bounds__(384, 1) void enc_layer_persist(
    const float* __restrict__ gi,   // [B*S][3072] = x@W + b0
    const float* __restrict__ U,    // [1024][3072]
    const float* __restrict__ b1,
    float* __restrict__ buf0,       // ping (zeroed), final state here
    float* __restrict__ buf1,       // pong
    float* __restrict__ seqout,     // [B*S][1024]
    int* __restrict__ flags,        // 256 flags, 128B apart, zeroed
    int base) {
    __shared__ float Us[12][1024];      // 48 KB  (colg = gate*4 + c)
    __shared__ float hs[32][260];       // 33.3 KB (one CH-chunk of h)
    __shared__ float ghs[12][33];       // reduced gh
    const int tid = threadIdx.x;
    const int c0 = blockIdx.x * 4;
    for (int i = tid; i < 12 * 1024; i += 384) {
        int colg = i % 12;
        int k = i / 12;
        Us[colg][k] = U[(size_t)k * G3 + (colg >> 2) * HH + c0 + (colg & 3)];
    }
    const int ks = tid & 31;        // k-slice 0..31
    const int outIdx = tid >> 5;    // 0..11
    const int cq = outIdx >> 2;     // gate 0..2
    const int mo = outIdx & 3;      // m-oct 0..3
    __syncthreads();
    for (int t = 0; t < SS; ++t) {
        const float* hin = (t & 1) ? buf1 : buf0;
        float* hout = (t & 1) ? buf0 : buf1;
        float acc[4][8];
#pragma unroll
        for (int a = 0; a < 4; ++a)
#pragma unroll
            for (int b = 0; b < 8; ++b) acc[a][b] = 0.f;
        for (int ch = 0; ch < HH / CH; ++ch) {
            for (int i = tid; i < 32 * (CH / 4); i += 384) {
                int m = i >> 6, q = i & 63;
                *(float4*)&hs[m][q * 4] =
                    *(const float4*)&hin[m * HH + ch * CH + q * 4];
            }
            __syncthreads();
#pragma unroll
            for (int j = 0; j < 2; ++j) {
                int kb = (j * 32 + ks) * 4;
                float4 uv[4];
#pragma unroll
                for (int ci = 0; ci < 4; ++ci)
                    uv[ci] = *(const float4*)&Us[cq * 4 + ci][ch * CH + kb];
#pragma unroll
                for (int mi = 0; mi < 8; ++mi) {
                    float4 hv = *(const float4*)&hs[mo * 8 + mi][kb];
#pragma unroll
                    for (int ci = 0; ci < 4; ++ci)
                        acc[ci][mi] += hv.x * uv[ci].x + hv.y * uv[ci].y +
                                       hv.z * uv[ci].z + hv.w * uv[ci].w;
                }
            }
            __syncthreads();
        }
#pragma unroll
        for (int ci = 0; ci < 4; ++ci)
#pragma unroll
            for (int mi = 0; mi < 8; ++mi) {
                float v = acc[ci][mi];
                v += __shfl_xor(v, 1, 64);
                v += __shfl_xor(v, 2, 64);
                v += __shfl_xor(v, 4, 64);
                v += __shfl_xor(v, 8, 64);
                v += __shfl_xor(v, 16, 64);
                if (ks == 0) ghs[cq * 4 + ci][mo * 8 + mi] = v;
            }
        __syncthreads();
        if (tid < 128) {
            int m = tid & 31, c = tid >> 5;      // c 0..3
            int col = c0 + c;
            float ghz = ghs[c][m] + b1[col];
            float ghr = ghs[4 + c][m] + b1[HH + col];
            float ghh = ghs[8 + c][m] + b1[2 * HH + col];
            const float* gir = gi + ((size_t)m * SS + t) * G3;
            float z = sigf(gir[col] + ghz);
            float r = sigf(gir[HH + col] + ghr);
            float nn = tanhf(gir[2 * HH + col] + r * ghh);
            float h = z * hin[m * HH + col] + (1.f - z) * nn;
            hout[m * HH + col] = h;
            seqout[((size_t)m * SS + t) * HH + col] = h;
        }
        // ---- flag-array grid barrier ----
        if (t < SS - 1) {
            __threadfence();
            __syncthreads();
            int want = base + t + 1;
            if (tid == 0)
                __hip_atomic_store(&flags[blockIdx.x * 32], want,
                                   __ATOMIC_RELEASE, __HIP_MEMORY_SCOPE_AGENT);
            if (tid < 256) {
                while (__hip_atomic_load(&flags[tid * 32], __ATOMIC_ACQUIRE,
                                         __HIP_MEMORY_SCOPE_AGENT) < want) {}
            }
            __syncthreads();
        }
    }
}

// ---------------- M=32 GEMM + optional fused per-block row-max ----------------
// grid N/128, 512 thr: nq = tid&31 (4 cols), mg = tid>>5 (2 m's). K%128==0.
__global__ __launch_bounds__(512) void mgemm(const float* __restrict__ A,
                                             const float* __restrict__ Bm,
                                             const float* __restrict__ bias,
                                             float* __restrict__ C,
                                             int K, int N, int ldc,
                                             float* __restrict__ pmv,
                                             int* __restrict__ pmi) {
    __shared__ float As_[128][36];   // transposed chunk [k][m]
    int tid = threadIdx.x;
    int nq = tid & 31, mg = tid >> 5;       // mg 0..15
    int ncol = blockIdx.x * 128 + nq * 4;
    const float* Bp = Bm + ncol;
    float acc[2][4] = {};
    for (int ch = 0; ch < K / 128; ++ch) {
#pragma unroll
        for (int it = 0; it < 2; ++it) {
            int idx = it * 512 + tid;      // 0..1023
            int m = idx >> 5, q = idx & 31;
            float4 v = *(const float4*)(A + (size_t)m * K + ch * 128 + q * 4);
            As_[q * 4 + 0][m] = v.x; As_[q * 4 + 1][m] = v.y;
            As_[q * 4 + 2][m] = v.z; As_[q * 4 + 3][m] = v.w;
        }
        __syncthreads();
#pragma unroll 4
        for (int k = 0; k < 128; ++k) {
            float2 av = *(const float2*)&As_[k][mg * 2];
            float4 bv = *(const float4*)(Bp + (size_t)(ch * 128 + k) * N);
            acc[0][0] += av.x * bv.x; acc[0][1] += av.x * bv.y;
            acc[0][2] += av.x * bv.z; acc[0][3] += av.x * bv.w;
            acc[1][0] += av.y * bv.x; acc[1][1] += av.y * bv.y;
            acc[1][2] += av.y * bv.z; acc[1][3] += av.y * bv.w;
        }
        __syncthreads();
    }
    float4 cv = *(const float4*)&bias[ncol];
#pragma unroll
    for (int mi = 0; mi < 2; ++mi) {
        acc[mi][0] += cv.x; acc[mi][1] += cv.y;
        acc[mi][2] += cv.z; acc[mi][3] += cv.w;
        int row = mg * 2 + mi;
        *(float4*)(C + (size_t)row * ldc + ncol) =
            make_float4(acc[mi][0], acc[mi][1], acc[mi][2], acc[mi][3]);
    }
    if (pmv) {
        int nbk = gridDim.x;
#pragma unroll
        for (int mi = 0; mi < 2; ++mi) {
            float best = acc[mi][0]; int bidx = ncol;
#pragma unroll
            for (int nj = 1; nj < 4; ++nj)
                if (acc[mi][nj] > best) { best = acc[mi][nj]; bidx = ncol + nj; }
#pragma unroll
            for (int o = 1; o < 32; o <<= 1) {
                float pv = __shfl_xor(best, o, 64);
                int pi = __shfl_xor(bidx, o, 64);
                if (pv > best || (pv == best && pi < bidx)) { best = pv; bidx = pi; }
            }
            if (nq == 0) {
                int row = mg * 2 + mi;
                pmv[row * nbk + blockIdx.x] = best;
                pmi[row * nbk + blockIdx.x] = bidx;
            }
        }
    }
}

// ---------------- fused decoder GRU (zero initial state), k-split x8 ----------------
// grid 128 blocks (8 h-cols each), 512 thr = 2 nq x 32 m x 8 kh.
__global__ __launch_bounds__(512) void dec_gru2(const float* __restrict__ A, int K,
                                                const float* __restrict__ W,
                                                const float* __restrict__ b0,
                                                const float* __restrict__ b1,
                                                float* __restrict__ hout) {
    __shared__ float part[7][64][13];
    int tid = threadIdx.x;
    int nq = tid & 1, m = (tid >> 1) & 31, kh = tid >> 6;   // kh 0..7
    int cb = blockIdx.x * 8 + nq * 4;
    float acc[3][4] = {};
    int kslice = K >> 3;
    const float* Ap = A + (size_t)m * K;
    int k0 = kh * kslice;
#pragma unroll 4
    for (int k = k0; k < k0 + kslice; ++k) {
        float av = Ap[k];
        const float* Wr = W + (size_t)k * G3 + cb;
#pragma unroll
        for (int g = 0; g < 3; ++g) {
            float4 wv = *(const float4*)(Wr + g * HH);
            acc[g][0] += av * wv.x; acc[g][1] += av * wv.y;
            acc[g][2] += av * wv.z; acc[g][3] += av * wv.w;
        }
    }
    int idx = m * 2 + nq;
    if (kh) {
#pragma unroll
        for (int g = 0; g < 3; ++g)
#pragma unroll
            for (int j = 0; j < 4; ++j)
                part[kh - 1][idx][g * 4 + j] = acc[g][j];
    }
    __syncthreads();
    if (kh == 0) {
        float vals[3][4];
#pragma unroll
        for (int g = 0; g < 3; ++g)
#pragma unroll
            for (int j = 0; j < 4; ++j) {
                float s = acc[g][j];
#pragma unroll
                for (int p = 0; p < 7; ++p) s += part[p][idx][g * 4 + j];
                vals[g][j] = s;
            }
        float4 hv;
        float* hvp = (float*)&hv;
#pragma unroll
        for (int j = 0; j < 4; ++j) {
            int c = cb + j;
            float z = sigf(vals[0][j] + b0[c] + b1[c]);
            float r = sigf(vals[1][j] + b0[HH + c] + b1[HH + c]);
            float nn = tanhf(vals[2][j] + b0[2 * HH + c] + r * b1[2 * HH + c]);
            hvp[j] = (1.f - z) * nn;
        }
        *(float4*)(hout + (size_t)m * HH + cb) = hv;
    }
}

// ---------------- fused argmax(prev logits) + Bahdanau attention + ctx ----------------
// One block per batch b. nb==0 -> use start token.
__global__ __launch_bounds__(256) void attn_ctx(const float* __restrict__ qb,
                                                const float* __restrict__ enc_proj,
                                                const float* __restrict__ enc_out,
                                                const float* __restrict__ vvec,
                                                const float* __restrict__ vb,
                                                const float* __restrict__ emb_fr,
                                                const int* __restrict__ start_id,
                                                const float* __restrict__ pmv,
                                                const int* __restrict__ pmi,
                                                int nb,
                                                float* __restrict__ xt) {
    int b = blockIdx.x;
    int tid = threadIdx.x;
    int wave = tid >> 6, lane = tid & 63;
    __shared__ float sc[SS];
    __shared__ float wsm[SS];
    __shared__ float sv[256];
    __shared__ int si[256];
    __shared__ int stok;
    if (nb == 0) {
        if (tid == 0) stok = start_id[0];
    } else {
        float best = -3.4e38f; int bi = 0x7fffffff;
        for (int i = tid; i < nb; i += 256) {
            float v = pmv[(size_t)b * nb + i];
            int ix = pmi[(size_t)b * nb + i];
            if (v > best || (v == best && ix < bi)) { best = v; bi = ix; }
        }
        sv[tid] = best; si[tid] = bi;
        __syncthreads();
        for (int s = 128; s; s >>= 1) {
            if (tid < s) {
                if (sv[tid + s] > sv[tid] ||
                    (sv[tid + s] == sv[tid] && si[tid + s] < si[tid])) {
                    sv[tid] = sv[tid + s]; si[tid] = si[tid + s];
                }
            }
            __syncthreads();
        }
        if (tid == 0) stok = si[0];
    }
    const float* q = qb + (size_t)b * HH;
    for (int s = wave; s < SS; s += 4) {
        const float* ep = enc_proj + (size_t)(b * SS + s) * HH;
        float sum = 0.f;
        for (int h = lane; h < HH; h += 64)
            sum += tanhf(q[h] + ep[h]) * vvec[h];
#pragma unroll
        for (int o = 32; o; o >>= 1) sum += __shfl_xor(sum, o, 64);
        if (lane == 0) sc[s] = sum + vb[0];
    }
    __syncthreads();
    if (tid < 64) {
        float v = (lane < SS) ? sc[lane] : -3.4e38f;
        float m = v;
#pragma unroll
        for (int o = 32; o; o >>= 1) m = fmaxf(m, __shfl_xor(m, o, 64));
        float e = (lane < SS) ? expf(v - m) : 0.f;
        float ssum = e;
#pragma unroll
        for (int o = 32; o; o >>= 1) ssum += __shfl_xor(ssum, o, 64);
        if (lane < SS) wsm[lane] = e / ssum;
    }
    __syncthreads();
    {
        float4 cx = make_float4(0.f, 0.f, 0.f, 0.f);
#pragma unroll 4
        for (int s = 0; s < SS; ++s) {
            float w = wsm[s];
            float4 e = *(const float4*)&enc_out[(size_t)(b * SS + s) * HH + tid * 4];
            cx.x += w * e.x; cx.y += w * e.y; cx.z += w * e.z; cx.w += w * e.w;
        }
        *(float4*)&xt[(size_t)b * (HH + EE) + tid * 4] = cx;
    }
    {
        int tok = stok;
        xt[(size_t)b * (HH + EE) + HH + tid] = emb_fr[(size_t)tok * EE + tid];
    }
}

// ---------------- decoder init: out[:,0,:] one-hot ----------------
__global__ __launch_bounds__(256) void init_dec(float* __restrict__ out,
                                                const int* __restrict__ start_id) {
    int idx = blockIdx.x * 256 + threadIdx.x;
    int sid = start_id[0];
    int b = idx / VOC, v = idx % VOC;
    out[(size_t)b * (GEN * VOC) + v] = (v == sid) ? 1.f : 0.f;
}

extern "C" void kernel_launch(void* const* d_in, const int* in_sizes, int n_in,
                              void* d_out, int out_size, void* d_ws, size_t ws_size,
                              hipStream_t stream) {
    const int*   inputs   = (const int*)d_in[0];
    const int*   start_id = (const int*)d_in[2];
    const float* emb_en   = (const float*)d_in[3];
    const float* emb_fr   = (const float*)d_in[4];
    const float* enc_W0   = (const float*)d_in[5];
    const float* enc_U0   = (const float*)d_in[6];
    const float* enc_b0   = (const float*)d_in[7];
    const float* enc_W1   = (const float*)d_in[8];
    const float* enc_U1   = (const float*)d_in[9];
    const float* enc_b1   = (const float*)d_in[10];
    const float* dec_W0   = (const float*)d_in[11];
    const float* dec_b0   = (const float*)d_in[13];
    const float* dec_W1   = (const float*)d_in[14];
    const float* dec_b1   = (const float*)d_in[16];
    const float* attn_W1  = (const float*)d_in[17];
    const float* attn_b1  = (const float*)d_in[18];
    const float* attn_W2  = (const float*)d_in[19];
    const float* attn_b2  = (const float*)d_in[20];
    const float* attn_V   = (const float*)d_in[21];
    const float* attn_Vb  = (const float*)d_in[22];
    const float* fc_W     = (const float*)d_in[23];
    const float* fc_b     = (const float*)d_in[24];
    float* out = (float*)d_out;
    float* ws  = (float*)d_ws;

    // workspace carve (floats)
    float* giA   = ws;                                // 4,718,592
    float* x_emb = giA + (size_t)BB * SS * G3;        // 393,216
    float* seq0  = x_emb + (size_t)BB * SS * EE;      // 1,572,864
    float* encO  = seq0 + (size_t)BB * SS * HH;       // 1,572,864
    float* encP  = encO + (size_t)BB * SS * HH;       // 1,572,864
    float* hA    = encP + (size_t)BB * SS * HH;       // 32,768
    float* hB    = hA + BB * HH;                      // 32,768
    float* qbuf  = hB + BB * HH;                      // 32,768
    float* xt    = qbuf + BB * HH;                    // 40,960
    float* h1    = xt + BB * (HH + EE);               // 32,768
    float* pmv   = h1 + BB * HH;                      // 32*250
    int*   pmi   = (int*)(pmv + 32 * 250);            // 32*250
    int*   flags = pmi + 32 * 250;                    // 256*32 ints (128B pad)

    hipMemsetAsync(flags, 0, 256 * 32 * sizeof(int), stream);

    // ---- encoder ----
    embed_en_k<<<(BB * SS * EE) / 256, 256, 0, stream>>>(inputs, emb_en, x_emb);
    gemm128<<<dim3(G3 / 128, (BB * SS) / 128), 256, 0, stream>>>(
        x_emb, enc_W0, enc_b0, giA, G3, EE);
    hipMemsetAsync(hA, 0, 2 * BB * HH * sizeof(float), stream);
    enc_layer_persist<<<256, 384, 0, stream>>>(giA, enc_U0, enc_b0 + G3,
                                               hA, hB, seq0, flags, 0);
    gemm128<<<dim3(G3 / 128, (BB * SS) / 128), 256, 0, stream>>>(
        seq0, enc_W1, enc_b1, giA, G3, HH);
    hipMemsetAsync(hA, 0, 2 * BB * HH * sizeof(float), stream);
    enc_layer_persist<<<256, 384, 0, stream>>>(giA, enc_U1, enc_b1 + G3,
                                               hA, hB, encO, flags, SS);
    // final hidden now in hA
    gemm128<<<dim3(HH / 128, (BB * SS) / 128), 256, 0, stream>>>(
        encO, attn_W2, attn_b2, encP, HH, HH);

    // ---- decoder ----
    init_dec<<<(BB * VOC) / 256, 256, 0, stream>>>(out, start_id);
    for (int step = 1; step < GEN; ++step) {
        mgemm<<<HH / 128, 512, 0, stream>>>(hA, attn_W1, attn_b1, qbuf,
                                            HH, HH, HH, nullptr, nullptr);
        attn_ctx<<<BB, 256, 0, stream>>>(qbuf, encP, encO, attn_V, attn_Vb,
                                         emb_fr, start_id, pmv, pmi,
                                         (step == 1) ? 0 : (VOC / 128), xt);
        dec_gru2<<<HH / 8, 512, 0, stream>>>(xt, HH + EE, dec_W0, dec_b0,
                                             dec_b0 + G3, h1);
        dec_gru2<<<HH / 8, 512, 0, stream>>>(h1, HH, dec_W1, dec_b1,
                                             dec_b1 + G3, hA);
        mgemm<<<VOC / 128, 512, 0, stream>>>(hA, fc_W, fc_b,
                                             out + (size_t)step * VOC,
                                             HH, VOC, GEN * VOC, pmv, pmi);
    }
}

// Round 4
// 25360.535 us; speedup vs baseline: 1.5838x; 1.0153x over previous
//
#include <hip/hip_runtime.h>
#include <math.h>

#define BB 32
#define SS 48
#define HH 1024
#define EE 256
#define VOC 32000
#define GEN 32
#define G3 3072
#define CH 256   // k-chunk for encoder step LDS staging

__device__ __forceinline__ float sigf(float x) { return 1.f / (1.f + expf(-x)); }

// ---------------- embedding for encoder input ----------------
__global__ __launch_bounds__(256) void embed_en_k(const int* __restrict__ inputs,
                                                  const float* __restrict__ emb,
                                                  float* __restrict__ x) {
    int i = blockIdx.x * 256 + threadIdx.x;   // < BB*SS*EE
    int row = i >> 8;
    int e = i & 255;
    x[i] = emb[(size_t)inputs[row] * EE + e];
}

// ---------------- 32x32 tiled transpose: U[1024][3072] -> UT[3072][1024] ----------------
__global__ __launch_bounds__(256) void transpose_k(const float* __restrict__ U,
                                                   float* __restrict__ UT) {
    __shared__ float t[32][33];
    int tx = threadIdx.x & 31, ty = threadIdx.x >> 5;   // ty 0..7
    int bx = blockIdx.x * 32;    // col base (3072 dim)
    int by = blockIdx.y * 32;    // k base (1024 dim)
#pragma unroll
    for (int i = 0; i < 4; ++i)
        t[ty + 8 * i][tx] = U[(size_t)(by + ty + 8 * i) * G3 + bx + tx];
    __syncthreads();
#pragma unroll
    for (int i = 0; i < 4; ++i)
        UT[(size_t)(bx + ty + 8 * i) * HH + by + tx] = t[tx][ty + 8 * i];
}

// ---------------- fp32 GEMM 128x128 tile, 8x8 micro ----------------
__global__ __launch_bounds__(256) void gemm128(const float* __restrict__ A,
                                               const float* __restrict__ Bm,
                                               const float* __restrict__ bias,
                                               float* __restrict__ C,
                                               int N, int K) {
    __shared__ float As[16][132];
    __shared__ float Bs[16][132];
    int tid = threadIdx.x;
    int tx = tid & 15, ty = tid >> 4;
    int arow = blockIdx.y * 128, bcol = blockIdx.x * 128;
    int am = tid >> 1;            // 0..127
    int ak = (tid & 1) * 8;       // 0 or 8
    int bk = tid >> 4;            // 0..15
    int bn = (tid & 15) * 8;      // 0..120
    float acc[8][8] = {};
    for (int k0 = 0; k0 < K; k0 += 16) {
        float4 a0 = *(const float4*)(A + (size_t)(arow + am) * K + k0 + ak);
        float4 a1 = *(const float4*)(A + (size_t)(arow + am) * K + k0 + ak + 4);
        float4 b0 = *(const float4*)(Bm + (size_t)(k0 + bk) * N + bcol + bn);
        float4 b1 = *(const float4*)(Bm + (size_t)(k0 + bk) * N + bcol + bn + 4);
        As[ak + 0][am] = a0.x; As[ak + 1][am] = a0.y;
        As[ak + 2][am] = a0.z; As[ak + 3][am] = a0.w;
        As[ak + 4][am] = a1.x; As[ak + 5][am] = a1.y;
        As[ak + 6][am] = a1.z; As[ak + 7][am] = a1.w;
        *(float4*)&Bs[bk][bn] = b0;
        *(float4*)&Bs[bk][bn + 4] = b1;
        __syncthreads();
#pragma unroll
        for (int kk = 0; kk < 16; ++kk) {
            float a[8], b[8];
            *(float4*)&a[0] = *(const float4*)&As[kk][ty * 8];
            *(float4*)&a[4] = *(const float4*)&As[kk][ty * 8 + 4];
            *(float4*)&b[0] = *(const float4*)&Bs[kk][tx * 8];
            *(float4*)&b[4] = *(const float4*)&Bs[kk][tx * 8 + 4];
#pragma unroll
            for (int i = 0; i < 8; ++i)
#pragma unroll
                for (int j = 0; j < 8; ++j) acc[i][j] += a[i] * b[j];
        }
        __syncthreads();
    }
    float bb[8];
    *(float4*)&bb[0] = *(const float4*)&bias[bcol + tx * 8];
    *(float4*)&bb[4] = *(const float4*)&bias[bcol + tx * 8 + 4];
#pragma unroll
    for (int i = 0; i < 8; ++i) {
        size_t row = arow + ty * 8 + i;
        float4 o0 = make_float4(acc[i][0] + bb[0], acc[i][1] + bb[1],
                                acc[i][2] + bb[2], acc[i][3] + bb[3]);
        float4 o1 = make_float4(acc[i][4] + bb[4], acc[i][5] + bb[5],
                                acc[i][6] + bb[6], acc[i][7] + bb[7]);
        *(float4*)(C + row * N + bcol + tx * 8) = o0;
        *(float4*)(C + row * N + bcol + tx * 8 + 4) = o1;
    }
}

// ---------------- per-step encoder GRU (launched 48x per layer) ----------------
// grid 256 blocks x 384 threads. Block owns 4 h-cols (12 gate-cols); loads its
// U slice coalesced from pre-transposed UT[3072][1024] into LDS each step
// (48KB, L2-resident). Same math as the old persistent body; kernel-launch
// boundaries provide cross-XCD coherence (no software barrier).
__global__ __launch_bounds__(384, 1) void enc_step(
    const float* __restrict__ gi,   // [B*S][3072] = x@W + b0
    const float* __restrict__ UT,   // [3072][1024] transposed U
    const float* __restrict__ b1,
    const float* __restrict__ hin,
    float* __restrict__ hout,
    float* __restrict__ seqout,     // [B*S][1024]
    int t) {
    __shared__ float Us[12][1024];      // 48 KB
    __shared__ float hs[32][260];       // 33.3 KB
    __shared__ float ghs[12][33];
    const int tid = threadIdx.x;
    const int c0 = blockIdx.x * 4;
    // coalesced U-slice load: 12 rows of UT, contiguous in k
    for (int i = tid; i < 12 * 256; i += 384) {
        int colg = i >> 8, kq = i & 255;
        int gcol = (colg >> 2) * HH + c0 + (colg & 3);
        *(float4*)&Us[colg][kq * 4] = *(const float4*)&UT[(size_t)gcol * HH + kq * 4];
    }
    const int ks = tid & 31;        // k-slice 0..31
    const int outIdx = tid >> 5;    // 0..11
    const int cq = outIdx >> 2;     // gate 0..2
    const int mo = outIdx & 3;      // m-oct 0..3
    float acc[4][8];
#pragma unroll
    for (int a = 0; a < 4; ++a)
#pragma unroll
        for (int b = 0; b < 8; ++b) acc[a][b] = 0.f;
    __syncthreads();
    for (int ch = 0; ch < HH / CH; ++ch) {
        for (int i = tid; i < 32 * (CH / 4); i += 384) {
            int m = i >> 6, q = i & 63;
            *(float4*)&hs[m][q * 4] =
                *(const float4*)&hin[m * HH + ch * CH + q * 4];
        }
        __syncthreads();
#pragma unroll
        for (int j = 0; j < 2; ++j) {
            int kb = (j * 32 + ks) * 4;
            float4 uv[4];
#pragma unroll
            for (int ci = 0; ci < 4; ++ci)
                uv[ci] = *(const float4*)&Us[cq * 4 + ci][ch * CH + kb];
#pragma unroll
            for (int mi = 0; mi < 8; ++mi) {
                float4 hv = *(const float4*)&hs[mo * 8 + mi][kb];
#pragma unroll
                for (int ci = 0; ci < 4; ++ci)
                    acc[ci][mi] += hv.x * uv[ci].x + hv.y * uv[ci].y +
                                   hv.z * uv[ci].z + hv.w * uv[ci].w;
            }
        }
        __syncthreads();
    }
#pragma unroll
    for (int ci = 0; ci < 4; ++ci)
#pragma unroll
        for (int mi = 0; mi < 8; ++mi) {
            float v = acc[ci][mi];
            v += __shfl_xor(v, 1, 64);
            v += __shfl_xor(v, 2, 64);
            v += __shfl_xor(v, 4, 64);
            v += __shfl_xor(v, 8, 64);
            v += __shfl_xor(v, 16, 64);
            if (ks == 0) ghs[cq * 4 + ci][mo * 8 + mi] = v;
        }
    __syncthreads();
    if (tid < 128) {
        int m = tid & 31, c = tid >> 5;      // c 0..3
        int col = c0 + c;
        float ghz = ghs[c][m] + b1[col];
        float ghr = ghs[4 + c][m] + b1[HH + col];
        float ghh = ghs[8 + c][m] + b1[2 * HH + col];
        const float* gir = gi + ((size_t)m * SS + t) * G3;
        float z = sigf(gir[col] + ghz);
        float r = sigf(gir[HH + col] + ghr);
        float nn = tanhf(gir[2 * HH + col] + r * ghh);
        float h = z * hin[m * HH + col] + (1.f - z) * nn;
        hout[m * HH + col] = h;
        seqout[((size_t)m * SS + t) * HH + col] = h;
    }
}

// ---------------- M=32 GEMM, templated N-tile + optional fused row-max ----------------
// NQ = BN/4 lanes per row-group; MG = TPB/NQ m-groups; RPT = 32/MG rows/thread.
template <int BN, int TPB>
__global__ __launch_bounds__(TPB) void mgemm(const float* __restrict__ A,
                                             const float* __restrict__ Bm,
                                             const float* __restrict__ bias,
                                             float* __restrict__ C,
                                             int K, int N, int ldc,
                                             float* __restrict__ pmv,
                                             int* __restrict__ pmi) {
    constexpr int NQ = BN / 4;
    constexpr int MG = TPB / NQ;
    constexpr int RPT = 32 / MG;
    __shared__ float As_[128][36];   // transposed chunk [k][m]
    int tid = threadIdx.x;
    int nq = tid % NQ, mg = tid / NQ;
    int ncol = blockIdx.x * BN + nq * 4;
    const float* Bp = Bm + ncol;
    float acc[RPT][4] = {};
    for (int ch = 0; ch < K / 128; ++ch) {
        for (int idx = tid; idx < 1024; idx += TPB) {
            int m = idx >> 5, q = idx & 31;
            float4 v = *(const float4*)(A + (size_t)m * K + ch * 128 + q * 4);
            As_[q * 4 + 0][m] = v.x; As_[q * 4 + 1][m] = v.y;
            As_[q * 4 + 2][m] = v.z; As_[q * 4 + 3][m] = v.w;
        }
        __syncthreads();
        // double-buffered B stream
        float4 bv = *(const float4*)(Bp + (size_t)(ch * 128) * N);
#pragma unroll 4
        for (int k = 0; k < 128; ++k) {
            float4 bnext;
            if (k < 127)
                bnext = *(const float4*)(Bp + (size_t)(ch * 128 + k + 1) * N);
#pragma unroll
            for (int r = 0; r < RPT; ++r) {
                float av = As_[k][mg * RPT + r];
                acc[r][0] += av * bv.x; acc[r][1] += av * bv.y;
                acc[r][2] += av * bv.z; acc[r][3] += av * bv.w;
            }
            bv = bnext;
        }
        __syncthreads();
    }
    float4 cv = *(const float4*)&bias[ncol];
#pragma unroll
    for (int r = 0; r < RPT; ++r) {
        acc[r][0] += cv.x; acc[r][1] += cv.y;
        acc[r][2] += cv.z; acc[r][3] += cv.w;
        int row = mg * RPT + r;
        *(float4*)(C + (size_t)row * ldc + ncol) =
            make_float4(acc[r][0], acc[r][1], acc[r][2], acc[r][3]);
    }
    if (pmv) {
        int nbk = gridDim.x;
#pragma unroll
        for (int r = 0; r < RPT; ++r) {
            float best = acc[r][0]; int bidx = ncol;
#pragma unroll
            for (int nj = 1; nj < 4; ++nj)
                if (acc[r][nj] > best) { best = acc[r][nj]; bidx = ncol + nj; }
#pragma unroll
            for (int o = 1; o < NQ; o <<= 1) {
                float pv = __shfl_xor(best, o, 64);
                int pi = __shfl_xor(bidx, o, 64);
                if (pv > best || (pv == best && pi < bidx)) { best = pv; bidx = pi; }
            }
            if (nq == 0) {
                int row = mg * RPT + r;
                pmv[row * nbk + blockIdx.x] = best;
                pmi[row * nbk + blockIdx.x] = bidx;
            }
        }
    }
}

// ---------------- fused decoder GRU (zero initial state), k-split x8 ----------------
__global__ __launch_bounds__(512) void dec_gru2(const float* __restrict__ A, int K,
                                                const float* __restrict__ W,
                                                const float* __restrict__ b0,
                                                const float* __restrict__ b1,
                                                float* __restrict__ hout) {
    __shared__ float part[7][64][13];
    int tid = threadIdx.x;
    int nq = tid & 1, m = (tid >> 1) & 31, kh = tid >> 6;   // kh 0..7
    int cb = blockIdx.x * 8 + nq * 4;
    float acc[3][4] = {};
    int kslice = K >> 3;
    const float* Ap = A + (size_t)m * K;
    int k0 = kh * kslice;
#pragma unroll 4
    for (int k = k0; k < k0 + kslice; ++k) {
        float av = Ap[k];
        const float* Wr = W + (size_t)k * G3 + cb;
#pragma unroll
        for (int g = 0; g < 3; ++g) {
            float4 wv = *(const float4*)(Wr + g * HH);
            acc[g][0] += av * wv.x; acc[g][1] += av * wv.y;
            acc[g][2] += av * wv.z; acc[g][3] += av * wv.w;
        }
    }
    int idx = m * 2 + nq;
    if (kh) {
#pragma unroll
        for (int g = 0; g < 3; ++g)
#pragma unroll
            for (int j = 0; j < 4; ++j)
                part[kh - 1][idx][g * 4 + j] = acc[g][j];
    }
    __syncthreads();
    if (kh == 0) {
        float vals[3][4];
#pragma unroll
        for (int g = 0; g < 3; ++g)
#pragma unroll
            for (int j = 0; j < 4; ++j) {
                float s = acc[g][j];
#pragma unroll
                for (int p = 0; p < 7; ++p) s += part[p][idx][g * 4 + j];
                vals[g][j] = s;
            }
        float4 hv;
        float* hvp = (float*)&hv;
#pragma unroll
        for (int j = 0; j < 4; ++j) {
            int c = cb + j;
            float z = sigf(vals[0][j] + b0[c] + b1[c]);
            float r = sigf(vals[1][j] + b0[HH + c] + b1[HH + c]);
            float nn = tanhf(vals[2][j] + b0[2 * HH + c] + r * b1[2 * HH + c]);
            hvp[j] = (1.f - z) * nn;
        }
        *(float4*)(hout + (size_t)m * HH + cb) = hv;
    }
}

// ---------------- fused argmax(prev logits) + Bahdanau attention + ctx ----------------
__global__ __launch_bounds__(256) void attn_ctx(const float* __restrict__ qb,
                                                const float* __restrict__ enc_proj,
                                                const float* __restrict__ enc_out,
                                                const float* __restrict__ vvec,
                                                const float* __restrict__ vb,
                                                const float* __restrict__ emb_fr,
                                                const int* __restrict__ start_id,
                                                const float* __restrict__ pmv,
                                                const int* __restrict__ pmi,
                                                int nb,
                                                float* __restrict__ xt) {
    int b = blockIdx.x;
    int tid = threadIdx.x;
    int wave = tid >> 6, lane = tid & 63;
    __shared__ float sc[SS];
    __shared__ float wsm[SS];
    __shared__ float sv[256];
    __shared__ int si[256];
    __shared__ int stok;
    if (nb == 0) {
        if (tid == 0) stok = start_id[0];
    } else {
        float best = -3.4e38f; int bi = 0x7fffffff;
        for (int i = tid; i < nb; i += 256) {
            float v = pmv[(size_t)b * nb + i];
            int ix = pmi[(size_t)b * nb + i];
            if (v > best || (v == best && ix < bi)) { best = v; bi = ix; }
        }
        sv[tid] = best; si[tid] = bi;
        __syncthreads();
        for (int s = 128; s; s >>= 1) {
            if (tid < s) {
                if (sv[tid + s] > sv[tid] ||
                    (sv[tid + s] == sv[tid] && si[tid + s] < si[tid])) {
                    sv[tid] = sv[tid + s]; si[tid] = si[tid + s];
                }
            }
            __syncthreads();
        }
        if (tid == 0) stok = si[0];
    }
    const float* q = qb + (size_t)b * HH;
    for (int s = wave; s < SS; s += 4) {
        const float* ep = enc_proj + (size_t)(b * SS + s) * HH;
        float sum = 0.f;
        for (int h = lane; h < HH; h += 64)
            sum += tanhf(q[h] + ep[h]) * vvec[h];
#pragma unroll
        for (int o = 32; o; o >>= 1) sum += __shfl_xor(sum, o, 64);
        if (lane == 0) sc[s] = sum + vb[0];
    }
    __syncthreads();
    if (tid < 64) {
        float v = (lane < SS) ? sc[lane] : -3.4e38f;
        float m = v;
#pragma unroll
        for (int o = 32; o; o >>= 1) m = fmaxf(m, __shfl_xor(m, o, 64));
        float e = (lane < SS) ? expf(v - m) : 0.f;
        float ssum = e;
#pragma unroll
        for (int o = 32; o; o >>= 1) ssum += __shfl_xor(ssum, o, 64);
        if (lane < SS) wsm[lane] = e / ssum;
    }
    __syncthreads();
    {
        float4 cx = make_float4(0.f, 0.f, 0.f, 0.f);
#pragma unroll 4
        for (int s = 0; s < SS; ++s) {
            float w = wsm[s];
            float4 e = *(const float4*)&enc_out[(size_t)(b * SS + s) * HH + tid * 4];
            cx.x += w * e.x; cx.y += w * e.y; cx.z += w * e.z; cx.w += w * e.w;
        }
        *(float4*)&xt[(size_t)b * (HH + EE) + tid * 4] = cx;
    }
    {
        int tok = stok;
        xt[(size_t)b * (HH + EE) + HH + tid] = emb_fr[(size_t)tok * EE + tid];
    }
}

// ---------------- decoder init: out[:,0,:] one-hot ----------------
__global__ __launch_bounds__(256) void init_dec(float* __restrict__ out,
                                                const int* __restrict__ start_id) {
    int idx = blockIdx.x * 256 + threadIdx.x;
    int sid = start_id[0];
    int b = idx / VOC, v = idx % VOC;
    out[(size_t)b * (GEN * VOC) + v] = (v == sid) ? 1.f : 0.f;
}

extern "C" void kernel_launch(void* const* d_in, const int* in_sizes, int n_in,
                              void* d_out, int out_size, void* d_ws, size_t ws_size,
                              hipStream_t stream) {
    const int*   inputs   = (const int*)d_in[0];
    const int*   start_id = (const int*)d_in[2];
    const float* emb_en   = (const float*)d_in[3];
    const float* emb_fr   = (const float*)d_in[4];
    const float* enc_W0   = (const float*)d_in[5];
    const float* enc_U0   = (const float*)d_in[6];
    const float* enc_b0   = (const float*)d_in[7];
    const float* enc_W1   = (const float*)d_in[8];
    const float* enc_U1   = (const float*)d_in[9];
    const float* enc_b1   = (const float*)d_in[10];
    const float* dec_W0   = (const float*)d_in[11];
    const float* dec_b0   = (const float*)d_in[13];
    const float* dec_W1   = (const float*)d_in[14];
    const float* dec_b1   = (const float*)d_in[16];
    const float* attn_W1  = (const float*)d_in[17];
    const float* attn_b1  = (const float*)d_in[18];
    const float* attn_W2  = (const float*)d_in[19];
    const float* attn_b2  = (const float*)d_in[20];
    const float* attn_V   = (const float*)d_in[21];
    const float* attn_Vb  = (const float*)d_in[22];
    const float* fc_W     = (const float*)d_in[23];
    const float* fc_b     = (const float*)d_in[24];
    float* out = (float*)d_out;
    float* ws  = (float*)d_ws;

    // workspace carve (floats)
    float* giA   = ws;                                // 4,718,592
    float* x_emb = giA + (size_t)BB * SS * G3;        // 393,216
    float* seq0  = x_emb + (size_t)BB * SS * EE;      // 1,572,864
    float* encO  = seq0 + (size_t)BB * SS * HH;       // 1,572,864
    float* encP  = encO + (size_t)BB * SS * HH;       // 1,572,864
    float* hA    = encP + (size_t)BB * SS * HH;       // 32,768
    float* hB    = hA + BB * HH;                      // 32,768
    float* qbuf  = hB + BB * HH;                      // 32,768
    float* xt    = qbuf + BB * HH;                    // 40,960
    float* h1    = xt + BB * (HH + EE);               // 32,768
    float* pmv   = h1 + BB * HH;                      // 32*500
    int*   pmi   = (int*)(pmv + 32 * 500);            // 32*500
    float* UT    = (float*)(pmi + 32 * 500);          // 3,145,728 (reused per layer)

    // ---- encoder ----
    embed_en_k<<<(BB * SS * EE) / 256, 256, 0, stream>>>(inputs, emb_en, x_emb);
    gemm128<<<dim3(G3 / 128, (BB * SS) / 128), 256, 0, stream>>>(
        x_emb, enc_W0, enc_b0, giA, G3, EE);
    transpose_k<<<dim3(96, 32), 256, 0, stream>>>(enc_U0, UT);
    hipMemsetAsync(hA, 0, BB * HH * sizeof(float), stream);
    for (int t = 0; t < SS; ++t) {
        const float* hin = (t & 1) ? hB : hA;
        float* hout = (t & 1) ? hA : hB;
        enc_step<<<256, 384, 0, stream>>>(giA, UT, enc_b0 + G3, hin, hout, seq0, t);
    }
    gemm128<<<dim3(G3 / 128, (BB * SS) / 128), 256, 0, stream>>>(
        seq0, enc_W1, enc_b1, giA, G3, HH);
    transpose_k<<<dim3(96, 32), 256, 0, stream>>>(enc_U1, UT);
    hipMemsetAsync(hA, 0, BB * HH * sizeof(float), stream);
    for (int t = 0; t < SS; ++t) {
        const float* hin = (t & 1) ? hB : hA;
        float* hout = (t & 1) ? hA : hB;
        enc_step<<<256, 384, 0, stream>>>(giA, UT, enc_b1 + G3, hin, hout, encO, t);
    }
    // final hidden now in hA (t=47 odd writes hA)
    gemm128<<<dim3(HH / 128, (BB * SS) / 128), 256, 0, stream>>>(
        encO, attn_W2, attn_b2, encP, HH, HH);

    // ---- decoder ----
    init_dec<<<(BB * VOC) / 256, 256, 0, stream>>>(out, start_id);
    for (int step = 1; step < GEN; ++step) {
        mgemm<32, 256><<<HH / 32, 256, 0, stream>>>(hA, attn_W1, attn_b1, qbuf,
                                                    HH, HH, HH, nullptr, nullptr);
        attn_ctx<<<BB, 256, 0, stream>>>(qbuf, encP, encO, attn_V, attn_Vb,
                                         emb_fr, start_id, pmv, pmi,
                                         (step == 1) ? 0 : (VOC / 64), xt);
        dec_gru2<<<HH / 8, 512, 0, stream>>>(xt, HH + EE, dec_W0, dec_b0,
                                             dec_b0 + G3, h1);
        dec_gru2<<<HH / 8, 512, 0, stream>>>(h1, HH, dec_W1, dec_b1,
                                             dec_b1 + G3, hA);
        mgemm<64, 256><<<VOC / 64, 256, 0, stream>>>(hA, fc_W, fc_b,
                                                     out + (size_t)step * VOC,
                                                     HH, VOC, GEN * VOC, pmv, pmi);
    }
}

// Round 5
// 10449.006 us; speedup vs baseline: 3.8440x; 2.4271x over previous
//
#include <hip/hip_runtime.h>
#include <math.h>

#define BB 32
#define SS 48
#define HH 1024
#define EE 256
#define VOC 32000
#define GEN 32
#define G3 3072
#define CH 256   // k-chunk for encoder step LDS staging

__device__ __forceinline__ float sigf(float x) { return 1.f / (1.f + expf(-x)); }

// ---------------- embedding for encoder input ----------------
__global__ __launch_bounds__(256) void embed_en_k(const int* __restrict__ inputs,
                                                  const float* __restrict__ emb,
                                                  float* __restrict__ x) {
    int i = blockIdx.x * 256 + threadIdx.x;   // < BB*SS*EE
    int row = i >> 8;
    int e = i & 255;
    x[i] = emb[(size_t)inputs[row] * EE + e];
}

// ---------------- 32x32 tiled transpose: U[1024][3072] -> UT[3072][1024] ----------------
__global__ __launch_bounds__(256) void transpose_k(const float* __restrict__ U,
                                                   float* __restrict__ UT) {
    __shared__ float t[32][33];
    int tx = threadIdx.x & 31, ty = threadIdx.x >> 5;   // ty 0..7
    int bx = blockIdx.x * 32;    // col base (3072 dim)
    int by = blockIdx.y * 32;    // k base (1024 dim)
#pragma unroll
    for (int i = 0; i < 4; ++i)
        t[ty + 8 * i][tx] = U[(size_t)(by + ty + 8 * i) * G3 + bx + tx];
    __syncthreads();
#pragma unroll
    for (int i = 0; i < 4; ++i)
        UT[(size_t)(bx + ty + 8 * i) * HH + by + tx] = t[tx][ty + 8 * i];
}

// ---------------- fp32 GEMM 128x128 tile, 8x8 micro ----------------
__global__ __launch_bounds__(256) void gemm128(const float* __restrict__ A,
                                               const float* __restrict__ Bm,
                                               const float* __restrict__ bias,
                                               float* __restrict__ C,
                                               int N, int K) {
    __shared__ float As[16][132];
    __shared__ float Bs[16][132];
    int tid = threadIdx.x;
    int tx = tid & 15, ty = tid >> 4;
    int arow = blockIdx.y * 128, bcol = blockIdx.x * 128;
    int am = tid >> 1;            // 0..127
    int ak = (tid & 1) * 8;       // 0 or 8
    int bk = tid >> 4;            // 0..15
    int bn = (tid & 15) * 8;      // 0..120
    float acc[8][8] = {};
    for (int k0 = 0; k0 < K; k0 += 16) {
        float4 a0 = *(const float4*)(A + (size_t)(arow + am) * K + k0 + ak);
        float4 a1 = *(const float4*)(A + (size_t)(arow + am) * K + k0 + ak + 4);
        float4 b0 = *(const float4*)(Bm + (size_t)(k0 + bk) * N + bcol + bn);
        float4 b1 = *(const float4*)(Bm + (size_t)(k0 + bk) * N + bcol + bn + 4);
        As[ak + 0][am] = a0.x; As[ak + 1][am] = a0.y;
        As[ak + 2][am] = a0.z; As[ak + 3][am] = a0.w;
        As[ak + 4][am] = a1.x; As[ak + 5][am] = a1.y;
        As[ak + 6][am] = a1.z; As[ak + 7][am] = a1.w;
        *(float4*)&Bs[bk][bn] = b0;
        *(float4*)&Bs[bk][bn + 4] = b1;
        __syncthreads();
#pragma unroll
        for (int kk = 0; kk < 16; ++kk) {
            float a[8], b[8];
            *(float4*)&a[0] = *(const float4*)&As[kk][ty * 8];
            *(float4*)&a[4] = *(const float4*)&As[kk][ty * 8 + 4];
            *(float4*)&b[0] = *(const float4*)&Bs[kk][tx * 8];
            *(float4*)&b[4] = *(const float4*)&Bs[kk][tx * 8 + 4];
#pragma unroll
            for (int i = 0; i < 8; ++i)
#pragma unroll
                for (int j = 0; j < 8; ++j) acc[i][j] += a[i] * b[j];
        }
        __syncthreads();
    }
    float bb[8];
    *(float4*)&bb[0] = *(const float4*)&bias[bcol + tx * 8];
    *(float4*)&bb[4] = *(const float4*)&bias[bcol + tx * 8 + 4];
#pragma unroll
    for (int i = 0; i < 8; ++i) {
        size_t row = arow + ty * 8 + i;
        float4 o0 = make_float4(acc[i][0] + bb[0], acc[i][1] + bb[1],
                                acc[i][2] + bb[2], acc[i][3] + bb[3]);
        float4 o1 = make_float4(acc[i][4] + bb[4], acc[i][5] + bb[5],
                                acc[i][6] + bb[6], acc[i][7] + bb[7]);
        *(float4*)(C + row * N + bcol + tx * 8) = o0;
        *(float4*)(C + row * N + bcol + tx * 8 + 4) = o1;
    }
}

// ---------------- per-step encoder GRU (launched 48x per layer) ----------------
// grid 256 x 384 threads. Block owns 4 h-cols (12 gate-cols). U read DIRECTLY
// from pre-transposed UT (coalesced: lanes ks 0..31 read consecutive float4s
// of one UT row; 48KB/block, L2-warm across steps). No U LDS staging.
__global__ __launch_bounds__(384) void enc_step(
    const float* __restrict__ gi,   // [B*S][3072] = x@W + b0
    const float* __restrict__ UT,   // [3072][1024] transposed U
    const float* __restrict__ b1,
    const float* __restrict__ hin,
    float* __restrict__ hout,
    float* __restrict__ seqout,     // [B*S][1024]
    int t) {
    __shared__ float hs[32][260];       // 33.3 KB
    __shared__ float ghs[12][33];
    const int tid = threadIdx.x;
    const int c0 = blockIdx.x * 4;
    const int ks = tid & 31;        // k-slice 0..31
    const int outIdx = tid >> 5;    // 0..11
    const int cq = outIdx >> 2;     // gate 0..2
    const int mo = outIdx & 3;      // m-oct 0..3
    const float* Ubase = UT + (size_t)(cq * HH + c0) * HH;   // +ci*HH rows
    float acc[4][8];
#pragma unroll
    for (int a = 0; a < 4; ++a)
#pragma unroll
        for (int b = 0; b < 8; ++b) acc[a][b] = 0.f;
    for (int ch = 0; ch < HH / CH; ++ch) {
        for (int i = tid; i < 32 * (CH / 4); i += 384) {
            int m = i >> 6, q = i & 63;
            *(float4*)&hs[m][q * 4] =
                *(const float4*)&hin[m * HH + ch * CH + q * 4];
        }
        __syncthreads();
#pragma unroll
        for (int j = 0; j < 2; ++j) {
            int kq = (j * 32 + ks) * 4;          // 0..255 within chunk
            float4 uv[4];
#pragma unroll
            for (int ci = 0; ci < 4; ++ci)
                uv[ci] = *(const float4*)&Ubase[(size_t)ci * HH + ch * CH + kq];
#pragma unroll
            for (int mi = 0; mi < 8; ++mi) {
                float4 hv = *(const float4*)&hs[mo * 8 + mi][kq];
#pragma unroll
                for (int ci = 0; ci < 4; ++ci)
                    acc[ci][mi] += hv.x * uv[ci].x + hv.y * uv[ci].y +
                                   hv.z * uv[ci].z + hv.w * uv[ci].w;
            }
        }
        __syncthreads();
    }
#pragma unroll
    for (int ci = 0; ci < 4; ++ci)
#pragma unroll
        for (int mi = 0; mi < 8; ++mi) {
            float v = acc[ci][mi];
            v += __shfl_xor(v, 1, 64);
            v += __shfl_xor(v, 2, 64);
            v += __shfl_xor(v, 4, 64);
            v += __shfl_xor(v, 8, 64);
            v += __shfl_xor(v, 16, 64);
            if (ks == 0) ghs[cq * 4 + ci][mo * 8 + mi] = v;
        }
    __syncthreads();
    if (tid < 128) {
        int m = tid & 31, c = tid >> 5;      // c 0..3
        int col = c0 + c;
        float ghz = ghs[c][m] + b1[col];
        float ghr = ghs[4 + c][m] + b1[HH + col];
        float ghh = ghs[8 + c][m] + b1[2 * HH + col];
        const float* gir = gi + ((size_t)m * SS + t) * G3;
        float z = sigf(gir[col] + ghz);
        float r = sigf(gir[HH + col] + ghr);
        float nn = tanhf(gir[2 * HH + col] + r * ghh);
        float h = z * hin[m * HH + col] + (1.f - z) * nn;
        hout[m * HH + col] = h;
        seqout[((size_t)m * SS + t) * HH + col] = h;
    }
}

// ---------------- coalesced-B small-M GEMM: C[32,N] = A[32,K]@B[K,N] + bias --------
// BM=32, BN=BN, BK=32, 256 thr. B staged via LDS with row-contiguous global
// loads (wave reads 512B contiguous) + register prefetch pipeline.
template <int BN, bool FMAX>
__global__ __launch_bounds__(256) void gemm_mn(const float* __restrict__ A,
                                               const float* __restrict__ Bm,
                                               const float* __restrict__ bias,
                                               float* __restrict__ C,
                                               int K, int N, int ldc,
                                               float* __restrict__ pmv,
                                               int* __restrict__ pmi) {
    constexpr int NX = BN / 8;          // 16 (BN=128) or 8 (BN=64)
    constexpr int NY = 256 / NX;        // 16 or 32
    constexpr int RPT = 32 / NY;        // 2 or 1
    constexpr int BLD = BN / 32;        // B float4 loads/thread: 4 or 2
    constexpr int BQ = BN / 4;          // float4s per B row
    __shared__ float As[32][33];
    __shared__ float Bs[32][BN + 4];
    int tid = threadIdx.x;
    int nx = tid % NX, ny = tid / NX;
    int bcol = blockIdx.x * BN;
    int nch = K / 32;
    int am = tid >> 3, aq = tid & 7;
    float4 ra = *(const float4*)(A + (size_t)am * K + aq * 4);
    float4 rb[BLD];
#pragma unroll
    for (int it = 0; it < BLD; ++it) {
        int lin = it * 256 + tid;
        int k = lin / BQ, q = lin % BQ;
        rb[it] = *(const float4*)(Bm + (size_t)k * N + bcol + q * 4);
    }
    float acc[RPT][8] = {};
    for (int ch = 0; ch < nch; ++ch) {
        __syncthreads();
        As[aq * 4 + 0][am] = ra.x; As[aq * 4 + 1][am] = ra.y;
        As[aq * 4 + 2][am] = ra.z; As[aq * 4 + 3][am] = ra.w;
#pragma unroll
        for (int it = 0; it < BLD; ++it) {
            int lin = it * 256 + tid;
            int k = lin / BQ, q = lin % BQ;
            *(float4*)&Bs[k][q * 4] = rb[it];
        }
        __syncthreads();
        if (ch + 1 < nch) {
            int k0 = (ch + 1) * 32;
            ra = *(const float4*)(A + (size_t)am * K + k0 + aq * 4);
#pragma unroll
            for (int it = 0; it < BLD; ++it) {
                int lin = it * 256 + tid;
                int k = lin / BQ, q = lin % BQ;
                rb[it] = *(const float4*)(Bm + (size_t)(k0 + k) * N + bcol + q * 4);
            }
        }
#pragma unroll
        for (int kk = 0; kk < 32; ++kk) {
            float a[RPT], b[8];
#pragma unroll
            for (int r = 0; r < RPT; ++r) a[r] = As[kk][ny * RPT + r];
            *(float4*)&b[0] = *(const float4*)&Bs[kk][nx * 8];
            *(float4*)&b[4] = *(const float4*)&Bs[kk][nx * 8 + 4];
#pragma unroll
            for (int r = 0; r < RPT; ++r)
#pragma unroll
                for (int j = 0; j < 8; ++j) acc[r][j] += a[r] * b[j];
        }
    }
    float bb[8];
    *(float4*)&bb[0] = *(const float4*)&bias[bcol + nx * 8];
    *(float4*)&bb[4] = *(const float4*)&bias[bcol + nx * 8 + 4];
#pragma unroll
    for (int r = 0; r < RPT; ++r) {
#pragma unroll
        for (int j = 0; j < 8; ++j) acc[r][j] += bb[j];
        int row = ny * RPT + r;
        *(float4*)(C + (size_t)row * ldc + bcol + nx * 8) =
            make_float4(acc[r][0], acc[r][1], acc[r][2], acc[r][3]);
        *(float4*)(C + (size_t)row * ldc + bcol + nx * 8 + 4) =
            make_float4(acc[r][4], acc[r][5], acc[r][6], acc[r][7]);
    }
    if (FMAX) {
        int nbk = gridDim.x;
#pragma unroll
        for (int r = 0; r < RPT; ++r) {
            float best = acc[r][0]; int bidx = bcol + nx * 8;
#pragma unroll
            for (int j = 1; j < 8; ++j)
                if (acc[r][j] > best) { best = acc[r][j]; bidx = bcol + nx * 8 + j; }
#pragma unroll
            for (int o = 1; o < NX; o <<= 1) {
                float pv = __shfl_xor(best, o, 64);
                int pi = __shfl_xor(bidx, o, 64);
                if (pv > best || (pv == best && pi < bidx)) { best = pv; bidx = pi; }
            }
            if (nx == 0) {
                int row = ny * RPT + r;
                pmv[row * nbk + blockIdx.x] = best;
                pmi[row * nbk + blockIdx.x] = bidx;
            }
        }
    }
}

// ---------------- fused decoder GRU (zero initial state), k-split x8 ----------------
__global__ __launch_bounds__(512) void dec_gru2(const float* __restrict__ A, int K,
                                                const float* __restrict__ W,
                                                const float* __restrict__ b0,
                                                const float* __restrict__ b1,
                                                float* __restrict__ hout) {
    __shared__ float part[7][64][13];
    int tid = threadIdx.x;
    int nq = tid & 1, m = (tid >> 1) & 31, kh = tid >> 6;   // kh 0..7
    int cb = blockIdx.x * 8 + nq * 4;
    float acc[3][4] = {};
    int kslice = K >> 3;
    const float* Ap = A + (size_t)m * K;
    int k0 = kh * kslice;
#pragma unroll 4
    for (int k = k0; k < k0 + kslice; ++k) {
        float av = Ap[k];
        const float* Wr = W + (size_t)k * G3 + cb;
#pragma unroll
        for (int g = 0; g < 3; ++g) {
            float4 wv = *(const float4*)(Wr + g * HH);
            acc[g][0] += av * wv.x; acc[g][1] += av * wv.y;
            acc[g][2] += av * wv.z; acc[g][3] += av * wv.w;
        }
    }
    int idx = m * 2 + nq;
    if (kh) {
#pragma unroll
        for (int g = 0; g < 3; ++g)
#pragma unroll
            for (int j = 0; j < 4; ++j)
                part[kh - 1][idx][g * 4 + j] = acc[g][j];
    }
    __syncthreads();
    if (kh == 0) {
        float vals[3][4];
#pragma unroll
        for (int g = 0; g < 3; ++g)
#pragma unroll
            for (int j = 0; j < 4; ++j) {
                float s = acc[g][j];
#pragma unroll
                for (int p = 0; p < 7; ++p) s += part[p][idx][g * 4 + j];
                vals[g][j] = s;
            }
        float4 hv;
        float* hvp = (float*)&hv;
#pragma unroll
        for (int j = 0; j < 4; ++j) {
            int c = cb + j;
            float z = sigf(vals[0][j] + b0[c] + b1[c]);
            float r = sigf(vals[1][j] + b0[HH + c] + b1[HH + c]);
            float nn = tanhf(vals[2][j] + b0[2 * HH + c] + r * b1[2 * HH + c]);
            hvp[j] = (1.f - z) * nn;
        }
        *(float4*)(hout + (size_t)m * HH + cb) = hv;
    }
}

// ---------------- fused argmax(prev logits) + Bahdanau attention + ctx ----------------
__global__ __launch_bounds__(512) void attn_ctx(const float* __restrict__ qb,
                                                const float* __restrict__ enc_proj,
                                                const float* __restrict__ enc_out,
                                                const float* __restrict__ vvec,
                                                const float* __restrict__ vb,
                                                const float* __restrict__ emb_fr,
                                                const int* __restrict__ start_id,
                                                const float* __restrict__ pmv,
                                                const int* __restrict__ pmi,
                                                int nb,
                                                float* __restrict__ xt) {
    int b = blockIdx.x;
    int tid = threadIdx.x;
    int wave = tid >> 6, lane = tid & 63;
    __shared__ float sc[SS];
    __shared__ float wsm[SS];
    __shared__ float sv[256];
    __shared__ int si[256];
    __shared__ int stok;
    if (nb == 0) {
        if (tid == 0) stok = start_id[0];
    } else {
        if (tid < 256) {
            float best = -3.4e38f; int bi = 0x7fffffff;
            for (int i = tid; i < nb; i += 256) {
                float v = pmv[(size_t)b * nb + i];
                int ix = pmi[(size_t)b * nb + i];
                if (v > best || (v == best && ix < bi)) { best = v; bi = ix; }
            }
            sv[tid] = best; si[tid] = bi;
        }
        __syncthreads();
        for (int s = 128; s; s >>= 1) {
            if (tid < s) {
                if (sv[tid + s] > sv[tid] ||
                    (sv[tid + s] == sv[tid] && si[tid + s] < si[tid])) {
                    sv[tid] = sv[tid + s]; si[tid] = si[tid + s];
                }
            }
            __syncthreads();
        }
        if (tid == 0) stok = si[0];
    }
    const float* q = qb + (size_t)b * HH;
    for (int s = wave; s < SS; s += 8) {
        const float* ep = enc_proj + (size_t)(b * SS + s) * HH;
        float sum = 0.f;
        for (int h = lane; h < HH; h += 64)
            sum += tanhf(q[h] + ep[h]) * vvec[h];
#pragma unroll
        for (int o = 32; o; o >>= 1) sum += __shfl_xor(sum, o, 64);
        if (lane == 0) sc[s] = sum + vb[0];
    }
    __syncthreads();
    if (tid < 64) {
        float v = (lane < SS) ? sc[lane] : -3.4e38f;
        float m = v;
#pragma unroll
        for (int o = 32; o; o >>= 1) m = fmaxf(m, __shfl_xor(m, o, 64));
        float e = (lane < SS) ? expf(v - m) : 0.f;
        float ssum = e;
#pragma unroll
        for (int o = 32; o; o >>= 1) ssum += __shfl_xor(ssum, o, 64);
        if (lane < SS) wsm[lane] = e / ssum;
    }
    __syncthreads();
    if (tid < 256) {
        float4 cx = make_float4(0.f, 0.f, 0.f, 0.f);
#pragma unroll 4
        for (int s = 0; s < SS; ++s) {
            float w = wsm[s];
            float4 e = *(const float4*)&enc_out[(size_t)(b * SS + s) * HH + tid * 4];
            cx.x += w * e.x; cx.y += w * e.y; cx.z += w * e.z; cx.w += w * e.w;
        }
        *(float4*)&xt[(size_t)b * (HH + EE) + tid * 4] = cx;
        xt[(size_t)b * (HH + EE) + HH + tid] = emb_fr[(size_t)stok * EE + tid];
    }
}

// ---------------- decoder init: out[:,0,:] one-hot ----------------
__global__ __launch_bounds__(256) void init_dec(float* __restrict__ out,
                                                const int* __restrict__ start_id) {
    int idx = blockIdx.x * 256 + threadIdx.x;
    int sid = start_id[0];
    int b = idx / VOC, v = idx % VOC;
    out[(size_t)b * (GEN * VOC) + v] = (v == sid) ? 1.f : 0.f;
}

extern "C" void kernel_launch(void* const* d_in, const int* in_sizes, int n_in,
                              void* d_out, int out_size, void* d_ws, size_t ws_size,
                              hipStream_t stream) {
    const int*   inputs   = (const int*)d_in[0];
    const int*   start_id = (const int*)d_in[2];
    const float* emb_en   = (const float*)d_in[3];
    const float* emb_fr   = (const float*)d_in[4];
    const float* enc_W0   = (const float*)d_in[5];
    const float* enc_U0   = (const float*)d_in[6];
    const float* enc_b0   = (const float*)d_in[7];
    const float* enc_W1   = (const float*)d_in[8];
    const float* enc_U1   = (const float*)d_in[9];
    const float* enc_b1   = (const float*)d_in[10];
    const float* dec_W0   = (const float*)d_in[11];
    const float* dec_b0   = (const float*)d_in[13];
    const float* dec_W1   = (const float*)d_in[14];
    const float* dec_b1   = (const float*)d_in[16];
    const float* attn_W1  = (const float*)d_in[17];
    const float* attn_b1  = (const float*)d_in[18];
    const float* attn_W2  = (const float*)d_in[19];
    const float* attn_b2  = (const float*)d_in[20];
    const float* attn_V   = (const float*)d_in[21];
    const float* attn_Vb  = (const float*)d_in[22];
    const float* fc_W     = (const float*)d_in[23];
    const float* fc_b     = (const float*)d_in[24];
    float* out = (float*)d_out;
    float* ws  = (float*)d_ws;

    // workspace carve (floats)
    float* giA   = ws;                                // 4,718,592
    float* x_emb = giA + (size_t)BB * SS * G3;        // 393,216
    float* seq0  = x_emb + (size_t)BB * SS * EE;      // 1,572,864
    float* encO  = seq0 + (size_t)BB * SS * HH;       // 1,572,864
    float* encP  = encO + (size_t)BB * SS * HH;       // 1,572,864
    float* hA    = encP + (size_t)BB * SS * HH;       // 32,768
    float* hB    = hA + BB * HH;                      // 32,768
    float* qbuf  = hB + BB * HH;                      // 32,768
    float* xt    = qbuf + BB * HH;                    // 40,960
    float* h1    = xt + BB * (HH + EE);               // 32,768
    float* pmv   = h1 + BB * HH;                      // 32*500
    int*   pmi   = (int*)(pmv + 32 * 500);            // 32*500
    float* UT    = (float*)(pmi + 32 * 500);          // 3,145,728 (reused per layer)

    // ---- encoder ----
    embed_en_k<<<(BB * SS * EE) / 256, 256, 0, stream>>>(inputs, emb_en, x_emb);
    gemm128<<<dim3(G3 / 128, (BB * SS) / 128), 256, 0, stream>>>(
        x_emb, enc_W0, enc_b0, giA, G3, EE);
    transpose_k<<<dim3(96, 32), 256, 0, stream>>>(enc_U0, UT);
    hipMemsetAsync(hA, 0, BB * HH * sizeof(float), stream);
    for (int t = 0; t < SS; ++t) {
        const float* hin = (t & 1) ? hB : hA;
        float* hout = (t & 1) ? hA : hB;
        enc_step<<<256, 384, 0, stream>>>(giA, UT, enc_b0 + G3, hin, hout, seq0, t);
    }
    gemm128<<<dim3(G3 / 128, (BB * SS) / 128), 256, 0, stream>>>(
        seq0, enc_W1, enc_b1, giA, G3, HH);
    transpose_k<<<dim3(96, 32), 256, 0, stream>>>(enc_U1, UT);
    hipMemsetAsync(hA, 0, BB * HH * sizeof(float), stream);
    for (int t = 0; t < SS; ++t) {
        const float* hin = (t & 1) ? hB : hA;
        float* hout = (t & 1) ? hA : hB;
        enc_step<<<256, 384, 0, stream>>>(giA, UT, enc_b1 + G3, hin, hout, encO, t);
    }
    // final hidden now in hA (t=47 odd writes hA)
    gemm128<<<dim3(HH / 128, (BB * SS) / 128), 256, 0, stream>>>(
        encO, attn_W2, attn_b2, encP, HH, HH);

    // ---- decoder ----
    init_dec<<<(BB * VOC) / 256, 256, 0, stream>>>(out, start_id);
    for (int step = 1; step < GEN; ++step) {
        gemm_mn<64, false><<<HH / 64, 256, 0, stream>>>(
            hA, attn_W1, attn_b1, qbuf, HH, HH, HH, nullptr, nullptr);
        attn_ctx<<<BB, 512, 0, stream>>>(qbuf, encP, encO, attn_V, attn_Vb,
                                         emb_fr, start_id, pmv, pmi,
                                         (step == 1) ? 0 : (VOC / 128), xt);
        dec_gru2<<<HH / 8, 512, 0, stream>>>(xt, HH + EE, dec_W0, dec_b0,
                                             dec_b0 + G3, h1);
        dec_gru2<<<HH / 8, 512, 0, stream>>>(h1, HH, dec_W1, dec_b1,
                                             dec_b1 + G3, hA);
        gemm_mn<128, true><<<VOC / 128, 256, 0, stream>>>(
            hA, fc_W, fc_b, out + (size_t)step * VOC,
            HH, VOC, GEN * VOC, pmv, pmi);
    }
}

// Round 6
// 9681.472 us; speedup vs baseline: 4.1488x; 1.0793x over previous
//
#include <hip/hip_runtime.h>
#include <math.h>

#define BB 32
#define SS 48
#define HH 1024
#define EE 256
#define VOC 32000
#define GEN 32
#define G3 3072
#define CH 256   // k-chunk for recurrent-step LDS staging

__device__ __forceinline__ float sigf(float x) { return 1.f / (1.f + expf(-x)); }

// ---------------- embedding for encoder input ----------------
__global__ __launch_bounds__(256) void embed_en_k(const int* __restrict__ inputs,
                                                  const float* __restrict__ emb,
                                                  float* __restrict__ x) {
    int i = blockIdx.x * 256 + threadIdx.x;   // < BB*SS*EE
    int row = i >> 8;
    int e = i & 255;
    x[i] = emb[(size_t)inputs[row] * EE + e];
}

// ---------------- 32x32 tiled transpose: U[R][C] -> UT[C][R] ----------------
__global__ __launch_bounds__(256) void transpose_k(const float* __restrict__ U,
                                                   float* __restrict__ UT,
                                                   int R, int C) {
    __shared__ float t[32][33];
    int tx = threadIdx.x & 31, ty = threadIdx.x >> 5;   // ty 0..7
    int bx = blockIdx.x * 32;    // col base (C dim)
    int by = blockIdx.y * 32;    // row base (R dim)
#pragma unroll
    for (int i = 0; i < 4; ++i)
        t[ty + 8 * i][tx] = U[(size_t)(by + ty + 8 * i) * C + bx + tx];
    __syncthreads();
#pragma unroll
    for (int i = 0; i < 4; ++i)
        UT[(size_t)(bx + ty + 8 * i) * R + by + tx] = t[tx][ty + 8 * i];
}

// ---------------- fp32 GEMM 128x128 tile, 8x8 micro ----------------
__global__ __launch_bounds__(256) void gemm128(const float* __restrict__ A,
                                               const float* __restrict__ Bm,
                                               const float* __restrict__ bias,
                                               float* __restrict__ C,
                                               int N, int K) {
    __shared__ float As[16][132];
    __shared__ float Bs[16][132];
    int tid = threadIdx.x;
    int tx = tid & 15, ty = tid >> 4;
    int arow = blockIdx.y * 128, bcol = blockIdx.x * 128;
    int am = tid >> 1;            // 0..127
    int ak = (tid & 1) * 8;       // 0 or 8
    int bk = tid >> 4;            // 0..15
    int bn = (tid & 15) * 8;      // 0..120
    float acc[8][8] = {};
    for (int k0 = 0; k0 < K; k0 += 16) {
        float4 a0 = *(const float4*)(A + (size_t)(arow + am) * K + k0 + ak);
        float4 a1 = *(const float4*)(A + (size_t)(arow + am) * K + k0 + ak + 4);
        float4 b0 = *(const float4*)(Bm + (size_t)(k0 + bk) * N + bcol + bn);
        float4 b1 = *(const float4*)(Bm + (size_t)(k0 + bk) * N + bcol + bn + 4);
        As[ak + 0][am] = a0.x; As[ak + 1][am] = a0.y;
        As[ak + 2][am] = a0.z; As[ak + 3][am] = a0.w;
        As[ak + 4][am] = a1.x; As[ak + 5][am] = a1.y;
        As[ak + 6][am] = a1.z; As[ak + 7][am] = a1.w;
        *(float4*)&Bs[bk][bn] = b0;
        *(float4*)&Bs[bk][bn + 4] = b1;
        __syncthreads();
#pragma unroll
        for (int kk = 0; kk < 16; ++kk) {
            float a[8], b[8];
            *(float4*)&a[0] = *(const float4*)&As[kk][ty * 8];
            *(float4*)&a[4] = *(const float4*)&As[kk][ty * 8 + 4];
            *(float4*)&b[0] = *(const float4*)&Bs[kk][tx * 8];
            *(float4*)&b[4] = *(const float4*)&Bs[kk][tx * 8 + 4];
#pragma unroll
            for (int i = 0; i < 8; ++i)
#pragma unroll
                for (int j = 0; j < 8; ++j) acc[i][j] += a[i] * b[j];
        }
        __syncthreads();
    }
    float bb[8];
    *(float4*)&bb[0] = *(const float4*)&bias[bcol + tx * 8];
    *(float4*)&bb[4] = *(const float4*)&bias[bcol + tx * 8 + 4];
#pragma unroll
    for (int i = 0; i < 8; ++i) {
        size_t row = arow + ty * 8 + i;
        float4 o0 = make_float4(acc[i][0] + bb[0], acc[i][1] + bb[1],
                                acc[i][2] + bb[2], acc[i][3] + bb[3]);
        float4 o1 = make_float4(acc[i][4] + bb[4], acc[i][5] + bb[5],
                                acc[i][6] + bb[6], acc[i][7] + bb[7]);
        *(float4*)(C + row * N + bcol + tx * 8) = o0;
        *(float4*)(C + row * N + bcol + tx * 8 + 4) = o1;
    }
}

// ---------------- per-step encoder GRU (launched 48x per layer) ----------------
// grid 256 x 384 threads. Block owns 4 h-cols (12 gate-cols). U read DIRECTLY
// from pre-transposed UT (coalesced; 48KB/block, L2-warm across steps).
__global__ __launch_bounds__(384) void enc_step(
    const float* __restrict__ gi,   // [B*S][3072] = x@W + b0
    const float* __restrict__ UT,   // [3072][1024] transposed U
    const float* __restrict__ b1,
    const float* __restrict__ hin,
    float* __restrict__ hout,
    float* __restrict__ seqout,     // [B*S][1024]
    int t) {
    __shared__ float hs[32][260];       // 33.3 KB
    __shared__ float ghs[12][33];
    const int tid = threadIdx.x;
    const int c0 = blockIdx.x * 4;
    const int ks = tid & 31;        // k-slice 0..31
    const int outIdx = tid >> 5;    // 0..11
    const int cq = outIdx >> 2;     // gate 0..2
    const int mo = outIdx & 3;      // m-oct 0..3
    const float* Ubase = UT + (size_t)(cq * HH + c0) * HH;   // +ci*HH rows
    float acc[4][8];
#pragma unroll
    for (int a = 0; a < 4; ++a)
#pragma unroll
        for (int b = 0; b < 8; ++b) acc[a][b] = 0.f;
    for (int ch = 0; ch < HH / CH; ++ch) {
        for (int i = tid; i < 32 * (CH / 4); i += 384) {
            int m = i >> 6, q = i & 63;
            *(float4*)&hs[m][q * 4] =
                *(const float4*)&hin[m * HH + ch * CH + q * 4];
        }
        __syncthreads();
#pragma unroll
        for (int j = 0; j < 2; ++j) {
            int kq = (j * 32 + ks) * 4;          // 0..255 within chunk
            float4 uv[4];
#pragma unroll
            for (int ci = 0; ci < 4; ++ci)
                uv[ci] = *(const float4*)&Ubase[(size_t)ci * HH + ch * CH + kq];
#pragma unroll
            for (int mi = 0; mi < 8; ++mi) {
                float4 hv = *(const float4*)&hs[mo * 8 + mi][kq];
#pragma unroll
                for (int ci = 0; ci < 4; ++ci)
                    acc[ci][mi] += hv.x * uv[ci].x + hv.y * uv[ci].y +
                                   hv.z * uv[ci].z + hv.w * uv[ci].w;
            }
        }
        __syncthreads();
    }
#pragma unroll
    for (int ci = 0; ci < 4; ++ci)
#pragma unroll
        for (int mi = 0; mi < 8; ++mi) {
            float v = acc[ci][mi];
            v += __shfl_xor(v, 1, 64);
            v += __shfl_xor(v, 2, 64);
            v += __shfl_xor(v, 4, 64);
            v += __shfl_xor(v, 8, 64);
            v += __shfl_xor(v, 16, 64);
            if (ks == 0) ghs[cq * 4 + ci][mo * 8 + mi] = v;
        }
    __syncthreads();
    if (tid < 128) {
        int m = tid & 31, c = tid >> 5;      // c 0..3
        int col = c0 + c;
        float ghz = ghs[c][m] + b1[col];
        float ghr = ghs[4 + c][m] + b1[HH + col];
        float ghh = ghs[8 + c][m] + b1[2 * HH + col];
        const float* gir = gi + ((size_t)m * SS + t) * G3;
        float z = sigf(gir[col] + ghz);
        float r = sigf(gir[HH + col] + ghr);
        float nn = tanhf(gir[2 * HH + col] + r * ghh);
        float h = z * hin[m * HH + col] + (1.f - z) * nn;
        hout[m * HH + col] = h;
        seqout[((size_t)m * SS + t) * HH + col] = h;
    }
}

// ---------------- decoder GRU step (zero initial state), WT-transposed ----------------
// raw = xt@W (via WT[3072][K], coalesced rows); z=sig(raw_z+b0z+b1z);
// r=sig(raw_r+b0r+b1r); n=tanh(raw_n+b0n+r*b1n); h=(1-z)*n.
// grid 256 x 384 threads, block owns 4 h-cols (12 gate-cols).
__global__ __launch_bounds__(384) void dec_step(
    const float* __restrict__ xt,   // [32][K]
    int K,
    const float* __restrict__ WT,   // [3072][K]
    const float* __restrict__ b0,
    const float* __restrict__ b1,
    float* __restrict__ hout) {
    __shared__ float hs[32][260];
    __shared__ float ghs[12][33];
    const int tid = threadIdx.x;
    const int c0 = blockIdx.x * 4;
    const int ks = tid & 31;
    const int outIdx = tid >> 5;    // 0..11
    const int cq = outIdx >> 2;     // gate 0..2
    const int mo = outIdx & 3;      // m-oct 0..3
    const float* Ubase = WT + (size_t)(cq * HH + c0) * K;
    float acc[4][8];
#pragma unroll
    for (int a = 0; a < 4; ++a)
#pragma unroll
        for (int b = 0; b < 8; ++b) acc[a][b] = 0.f;
    const int nch = K / CH;
    for (int ch = 0; ch < nch; ++ch) {
        for (int i = tid; i < 32 * (CH / 4); i += 384) {
            int m = i >> 6, q = i & 63;
            *(float4*)&hs[m][q * 4] =
                *(const float4*)&xt[(size_t)m * K + ch * CH + q * 4];
        }
        __syncthreads();
#pragma unroll
        for (int j = 0; j < 2; ++j) {
            int kq = (j * 32 + ks) * 4;
            float4 uv[4];
#pragma unroll
            for (int ci = 0; ci < 4; ++ci)
                uv[ci] = *(const float4*)&Ubase[(size_t)ci * K + ch * CH + kq];
#pragma unroll
            for (int mi = 0; mi < 8; ++mi) {
                float4 hv = *(const float4*)&hs[mo * 8 + mi][kq];
#pragma unroll
                for (int ci = 0; ci < 4; ++ci)
                    acc[ci][mi] += hv.x * uv[ci].x + hv.y * uv[ci].y +
                                   hv.z * uv[ci].z + hv.w * uv[ci].w;
            }
        }
        __syncthreads();
    }
#pragma unroll
    for (int ci = 0; ci < 4; ++ci)
#pragma unroll
        for (int mi = 0; mi < 8; ++mi) {
            float v = acc[ci][mi];
            v += __shfl_xor(v, 1, 64);
            v += __shfl_xor(v, 2, 64);
            v += __shfl_xor(v, 4, 64);
            v += __shfl_xor(v, 8, 64);
            v += __shfl_xor(v, 16, 64);
            if (ks == 0) ghs[cq * 4 + ci][mo * 8 + mi] = v;
        }
    __syncthreads();
    if (tid < 128) {
        int m = tid & 31, c = tid >> 5;
        int col = c0 + c;
        float z = sigf(ghs[c][m] + b0[col] + b1[col]);
        float r = sigf(ghs[4 + c][m] + b0[HH + col] + b1[HH + col]);
        float nn = tanhf(ghs[8 + c][m] + b0[2 * HH + col] + r * b1[2 * HH + col]);
        hout[m * HH + col] = (1.f - z) * nn;
    }
}

// ---------------- coalesced-B small-M GEMM: C[32,N] = A[32,K]@B[K,N] + bias --------
template <int BN, bool FMAX>
__global__ __launch_bounds__(256) void gemm_mn(const float* __restrict__ A,
                                               const float* __restrict__ Bm,
                                               const float* __restrict__ bias,
                                               float* __restrict__ C,
                                               int K, int N, int ldc,
                                               float* __restrict__ pmv,
                                               int* __restrict__ pmi) {
    constexpr int NX = BN / 8;          // 16 (BN=128) or 8 (BN=64)
    constexpr int NY = 256 / NX;        // 16 or 32
    constexpr int RPT = 32 / NY;        // 2 or 1
    constexpr int BLD = BN / 32;        // B float4 loads/thread
    constexpr int BQ = BN / 4;          // float4s per B row
    __shared__ float As[32][33];
    __shared__ float Bs[32][BN + 4];
    int tid = threadIdx.x;
    int nx = tid % NX, ny = tid / NX;
    int bcol = blockIdx.x * BN;
    int nch = K / 32;
    int am = tid >> 3, aq = tid & 7;
    float4 ra = *(const float4*)(A + (size_t)am * K + aq * 4);
    float4 rb[BLD];
#pragma unroll
    for (int it = 0; it < BLD; ++it) {
        int lin = it * 256 + tid;
        int k = lin / BQ, q = lin % BQ;
        rb[it] = *(const float4*)(Bm + (size_t)k * N + bcol + q * 4);
    }
    float acc[RPT][8] = {};
    for (int ch = 0; ch < nch; ++ch) {
        __syncthreads();
        As[aq * 4 + 0][am] = ra.x; As[aq * 4 + 1][am] = ra.y;
        As[aq * 4 + 2][am] = ra.z; As[aq * 4 + 3][am] = ra.w;
#pragma unroll
        for (int it = 0; it < BLD; ++it) {
            int lin = it * 256 + tid;
            int k = lin / BQ, q = lin % BQ;
            *(float4*)&Bs[k][q * 4] = rb[it];
        }
        __syncthreads();
        if (ch + 1 < nch) {
            int k0 = (ch + 1) * 32;
            ra = *(const float4*)(A + (size_t)am * K + k0 + aq * 4);
#pragma unroll
            for (int it = 0; it < BLD; ++it) {
                int lin = it * 256 + tid;
                int k = lin / BQ, q = lin % BQ;
                rb[it] = *(const float4*)(Bm + (size_t)(k0 + k) * N + bcol + q * 4);
            }
        }
#pragma unroll
        for (int kk = 0; kk < 32; ++kk) {
            float a[RPT], b[8];
#pragma unroll
            for (int r = 0; r < RPT; ++r) a[r] = As[kk][ny * RPT + r];
            *(float4*)&b[0] = *(const float4*)&Bs[kk][nx * 8];
            *(float4*)&b[4] = *(const float4*)&Bs[kk][nx * 8 + 4];
#pragma unroll
            for (int r = 0; r < RPT; ++r)
#pragma unroll
                for (int j = 0; j < 8; ++j) acc[r][j] += a[r] * b[j];
        }
    }
    float bb[8];
    *(float4*)&bb[0] = *(const float4*)&bias[bcol + nx * 8];
    *(float4*)&bb[4] = *(const float4*)&bias[bcol + nx * 8 + 4];
#pragma unroll
    for (int r = 0; r < RPT; ++r) {
#pragma unroll
        for (int j = 0; j < 8; ++j) acc[r][j] += bb[j];
        int row = ny * RPT + r;
        *(float4*)(C + (size_t)row * ldc + bcol + nx * 8) =
            make_float4(acc[r][0], acc[r][1], acc[r][2], acc[r][3]);
        *(float4*)(C + (size_t)row * ldc + bcol + nx * 8 + 4) =
            make_float4(acc[r][4], acc[r][5], acc[r][6], acc[r][7]);
    }
    if (FMAX) {
        int nbk = gridDim.x;
#pragma unroll
        for (int r = 0; r < RPT; ++r) {
            float best = acc[r][0]; int bidx = bcol + nx * 8;
#pragma unroll
            for (int j = 1; j < 8; ++j)
                if (acc[r][j] > best) { best = acc[r][j]; bidx = bcol + nx * 8 + j; }
#pragma unroll
            for (int o = 1; o < NX; o <<= 1) {
                float pv = __shfl_xor(best, o, 64);
                int pi = __shfl_xor(bidx, o, 64);
                if (pv > best || (pv == best && pi < bidx)) { best = pv; bidx = pi; }
            }
            if (nx == 0) {
                int row = ny * RPT + r;
                pmv[row * nbk + blockIdx.x] = best;
                pmi[row * nbk + blockIdx.x] = bidx;
            }
        }
    }
}

// ---------------- fused argmax(prev logits) + Bahdanau attention + ctx ----------------
__global__ __launch_bounds__(512) void attn_ctx(const float* __restrict__ qb,
                                                const float* __restrict__ enc_proj,
                                                const float* __restrict__ enc_out,
                                                const float* __restrict__ vvec,
                                                const float* __restrict__ vb,
                                                const float* __restrict__ emb_fr,
                                                const int* __restrict__ start_id,
                                                const float* __restrict__ pmv,
                                                const int* __restrict__ pmi,
                                                int nb,
                                                float* __restrict__ xt) {
    int b = blockIdx.x;
    int tid = threadIdx.x;
    int wave = tid >> 6, lane = tid & 63;
    __shared__ float sc[SS];
    __shared__ float wsm[SS];
    __shared__ float sv[256];
    __shared__ int si[256];
    __shared__ int stok;
    if (nb == 0) {
        if (tid == 0) stok = start_id[0];
    } else {
        if (tid < 256) {
            float best = -3.4e38f; int bi = 0x7fffffff;
            for (int i = tid; i < nb; i += 256) {
                float v = pmv[(size_t)b * nb + i];
                int ix = pmi[(size_t)b * nb + i];
                if (v > best || (v == best && ix < bi)) { best = v; bi = ix; }
            }
            sv[tid] = best; si[tid] = bi;
        }
        __syncthreads();
        for (int s = 128; s; s >>= 1) {
            if (tid < s) {
                if (sv[tid + s] > sv[tid] ||
                    (sv[tid + s] == sv[tid] && si[tid + s] < si[tid])) {
                    sv[tid] = sv[tid + s]; si[tid] = si[tid + s];
                }
            }
            __syncthreads();
        }
        if (tid == 0) stok = si[0];
    }
    const float* q = qb + (size_t)b * HH;
    for (int s = wave; s < SS; s += 8) {
        const float* ep = enc_proj + (size_t)(b * SS + s) * HH;
        float sum = 0.f;
        for (int h = lane; h < HH; h += 64)
            sum += tanhf(q[h] + ep[h]) * vvec[h];
#pragma unroll
        for (int o = 32; o; o >>= 1) sum += __shfl_xor(sum, o, 64);
        if (lane == 0) sc[s] = sum + vb[0];
    }
    __syncthreads();
    if (tid < 64) {
        float v = (lane < SS) ? sc[lane] : -3.4e38f;
        float m = v;
#pragma unroll
        for (int o = 32; o; o >>= 1) m = fmaxf(m, __shfl_xor(m, o, 64));
        float e = (lane < SS) ? expf(v - m) : 0.f;
        float ssum = e;
#pragma unroll
        for (int o = 32; o; o >>= 1) ssum += __shfl_xor(ssum, o, 64);
        if (lane < SS) wsm[lane] = e / ssum;
    }
    __syncthreads();
    if (tid < 256) {
        float4 cx = make_float4(0.f, 0.f, 0.f, 0.f);
#pragma unroll 4
        for (int s = 0; s < SS; ++s) {
            float w = wsm[s];
            float4 e = *(const float4*)&enc_out[(size_t)(b * SS + s) * HH + tid * 4];
            cx.x += w * e.x; cx.y += w * e.y; cx.z += w * e.z; cx.w += w * e.w;
        }
        *(float4*)&xt[(size_t)b * (HH + EE) + tid * 4] = cx;
        xt[(size_t)b * (HH + EE) + HH + tid] = emb_fr[(size_t)stok * EE + tid];
    }
}

// ---------------- decoder init: out[:,0,:] one-hot ----------------
__global__ __launch_bounds__(256) void init_dec(float* __restrict__ out,
                                                const int* __restrict__ start_id) {
    int idx = blockIdx.x * 256 + threadIdx.x;
    int sid = start_id[0];
    int b = idx / VOC, v = idx % VOC;
    out[(size_t)b * (GEN * VOC) + v] = (v == sid) ? 1.f : 0.f;
}

extern "C" void kernel_launch(void* const* d_in, const int* in_sizes, int n_in,
                              void* d_out, int out_size, void* d_ws, size_t ws_size,
                              hipStream_t stream) {
    const int*   inputs   = (const int*)d_in[0];
    const int*   start_id = (const int*)d_in[2];
    const float* emb_en   = (const float*)d_in[3];
    const float* emb_fr   = (const float*)d_in[4];
    const float* enc_W0   = (const float*)d_in[5];
    const float* enc_U0   = (const float*)d_in[6];
    const float* enc_b0   = (const float*)d_in[7];
    const float* enc_W1   = (const float*)d_in[8];
    const float* enc_U1   = (const float*)d_in[9];
    const float* enc_b1   = (const float*)d_in[10];
    const float* dec_W0   = (const float*)d_in[11];
    const float* dec_b0   = (const float*)d_in[13];
    const float* dec_W1   = (const float*)d_in[14];
    const float* dec_b1   = (const float*)d_in[16];
    const float* attn_W1  = (const float*)d_in[17];
    const float* attn_b1  = (const float*)d_in[18];
    const float* attn_W2  = (const float*)d_in[19];
    const float* attn_b2  = (const float*)d_in[20];
    const float* attn_V   = (const float*)d_in[21];
    const float* attn_Vb  = (const float*)d_in[22];
    const float* fc_W     = (const float*)d_in[23];
    const float* fc_b     = (const float*)d_in[24];
    float* out = (float*)d_out;
    float* ws  = (float*)d_ws;

    // workspace carve (floats)
    float* giA   = ws;                                // 4,718,592
    float* x_emb = giA + (size_t)BB * SS * G3;        // 393,216
    float* seq0  = x_emb + (size_t)BB * SS * EE;      // 1,572,864
    float* encO  = seq0 + (size_t)BB * SS * HH;       // 1,572,864
    float* encP  = encO + (size_t)BB * SS * HH;       // 1,572,864
    float* hA    = encP + (size_t)BB * SS * HH;       // 32,768
    float* hB    = hA + BB * HH;                      // 32,768
    float* qbuf  = hB + BB * HH;                      // 32,768
    float* xt    = qbuf + BB * HH;                    // 40,960
    float* h1    = xt + BB * (HH + EE);               // 32,768
    float* pmv   = h1 + BB * HH;                      // 32*500
    int*   pmi   = (int*)(pmv + 32 * 500);            // 32*500
    float* UT    = (float*)(pmi + 32 * 500);          // 3,145,728 (enc layers; then dec_W1T)
    float* WT0   = UT + (size_t)G3 * HH;              // 3,932,160 (dec_W0T [3072][1280])

    // ---- encoder ----
    embed_en_k<<<(BB * SS * EE) / 256, 256, 0, stream>>>(inputs, emb_en, x_emb);
    gemm128<<<dim3(G3 / 128, (BB * SS) / 128), 256, 0, stream>>>(
        x_emb, enc_W0, enc_b0, giA, G3, EE);
    transpose_k<<<dim3(96, 32), 256, 0, stream>>>(enc_U0, UT, HH, G3);
    hipMemsetAsync(hA, 0, BB * HH * sizeof(float), stream);
    for (int t = 0; t < SS; ++t) {
        const float* hin = (t & 1) ? hB : hA;
        float* hout = (t & 1) ? hA : hB;
        enc_step<<<256, 384, 0, stream>>>(giA, UT, enc_b0 + G3, hin, hout, seq0, t);
    }
    gemm128<<<dim3(G3 / 128, (BB * SS) / 128), 256, 0, stream>>>(
        seq0, enc_W1, enc_b1, giA, G3, HH);
    transpose_k<<<dim3(96, 32), 256, 0, stream>>>(enc_U1, UT, HH, G3);
    hipMemsetAsync(hA, 0, BB * HH * sizeof(float), stream);
    for (int t = 0; t < SS; ++t) {
        const float* hin = (t & 1) ? hB : hA;
        float* hout = (t & 1) ? hA : hB;
        enc_step<<<256, 384, 0, stream>>>(giA, UT, enc_b1 + G3, hin, hout, encO, t);
    }
    // final hidden now in hA (t=47 odd writes hA)
    gemm128<<<dim3(HH / 128, (BB * SS) / 128), 256, 0, stream>>>(
        encO, attn_W2, attn_b2, encP, HH, HH);

    // ---- decoder weight transposes (UT now free -> dec_W1T) ----
    transpose_k<<<dim3(96, 40), 256, 0, stream>>>(dec_W0, WT0, HH + EE, G3);
    transpose_k<<<dim3(96, 32), 256, 0, stream>>>(dec_W1, UT, HH, G3);

    // ---- decoder ----
    init_dec<<<(BB * VOC) / 256, 256, 0, stream>>>(out, start_id);
    for (int step = 1; step < GEN; ++step) {
        gemm_mn<64, false><<<HH / 64, 256, 0, stream>>>(
            hA, attn_W1, attn_b1, qbuf, HH, HH, HH, nullptr, nullptr);
        attn_ctx<<<BB, 512, 0, stream>>>(qbuf, encP, encO, attn_V, attn_Vb,
                                         emb_fr, start_id, pmv, pmi,
                                         (step == 1) ? 0 : (VOC / 128), xt);
        dec_step<<<256, 384, 0, stream>>>(xt, HH + EE, WT0, dec_b0,
                                          dec_b0 + G3, h1);
        dec_step<<<256, 384, 0, stream>>>(h1, HH, UT, dec_b1,
                                          dec_b1 + G3, hA);
        gemm_mn<128, true><<<VOC / 128, 256, 0, stream>>>(
            hA, fc_W, fc_b, out + (size_t)step * VOC,
            HH, VOC, GEN * VOC, pmv, pmi);
    }
}